// Round 1
// baseline (1330.108 us; speedup 1.0000x reference)
//
#include <hip/hip_runtime.h>
#include <math.h>

// MAGNN link prediction forward — fp32 throughout.
// Sizes fixed per reference.
#define NN0 20000
#define NN1 20000
#define NTOT 40000
#define FF0 512
#define HIDD 64
#define EEE 200000
#define BBB 8192
#define AVV 128
#define CHH 128

// ---------------- tower: Linear(512->64) + GELU + Linear(64->64) + residual + LN ----------------
__global__ __launch_bounds__(256) void tower_kernel(
    const float* __restrict__ x, const float* __restrict__ pw, const float* __restrict__ pb,
    const float* __restrict__ w2, const float* __restrict__ b2,
    const float* __restrict__ g, const float* __restrict__ be,
    const int* __restrict__ idx, float* __restrict__ feat, int nrows)
{
    __shared__ float xs[64][33];
    __shared__ float wsh[32][64];
    __shared__ float hs[64][65];
    __shared__ float w2s[64][64];
    int tid = threadIdx.x;
    int c = tid & 63, rq = tid >> 6;
    int row0 = blockIdx.x * 64;

    // stage w2 once (16KB, 2-way bank alias = free)
    for (int li = tid; li < 64 * 64; li += 256) w2s[li >> 6][li & 63] = w2[li];

    float acc[16];
#pragma unroll
    for (int i = 0; i < 16; i++) acc[i] = 0.f;

    for (int k0 = 0; k0 < FF0; k0 += 32) {
        // x tile 64x32 via float4
        for (int li = tid; li < 64 * 8; li += 256) {
            int r = li >> 3, k4 = li & 7;
            int gr = row0 + r;
            float4 v = make_float4(0.f, 0.f, 0.f, 0.f);
            if (gr < nrows) v = *(const float4*)&x[(long)gr * FF0 + k0 + k4 * 4];
            xs[r][k4 * 4 + 0] = v.x; xs[r][k4 * 4 + 1] = v.y;
            xs[r][k4 * 4 + 2] = v.z; xs[r][k4 * 4 + 3] = v.w;
        }
        // pw tile 32x64 via float4
        for (int li = tid; li < 32 * 16; li += 256) {
            int kk = li >> 4, c4 = li & 15;
            float4 v = *(const float4*)&pw[(long)(k0 + kk) * HIDD + c4 * 4];
            wsh[kk][c4 * 4 + 0] = v.x; wsh[kk][c4 * 4 + 1] = v.y;
            wsh[kk][c4 * 4 + 2] = v.z; wsh[kk][c4 * 4 + 3] = v.w;
        }
        __syncthreads();
#pragma unroll
        for (int kk = 0; kk < 32; kk++) {
            float wv = wsh[kk][c];
#pragma unroll
            for (int i = 0; i < 16; i++)
                acc[i] = fmaf(xs[rq + 4 * i][kk], wv, acc[i]);
        }
        __syncthreads();
    }

    float pbc = pb[c];
    float z[16];
#pragma unroll
    for (int i = 0; i < 16; i++) {
        z[i] = acc[i] + pbc;
        float h = 0.5f * z[i] * (1.f + erff(z[i] * 0.70710678118654752f)); // exact GELU
        hs[rq + 4 * i][c] = h;
    }
    __syncthreads();

    float b2c = b2[c], gc = g[c], bec = be[c];
#pragma unroll
    for (int i = 0; i < 16; i++) {
        int row = rq + 4 * i;
        float y = z[i] + b2c;
        for (int k = 0; k < 64; k++)
            y = fmaf(hs[row][k], w2s[k][c], y);
        // LayerNorm across the wave (64 lanes == 64 cols of this row)
        float mu = y;
        for (int off = 32; off; off >>= 1) mu += __shfl_xor(mu, off);
        mu *= (1.f / 64.f);
        float d = y - mu;
        float var = d * d;
        for (int off = 32; off; off >>= 1) var += __shfl_xor(var, off);
        var *= (1.f / 64.f);
        float o = d * (1.f / sqrtf(var + 1e-5f)) * gc + bec;
        int grow = row0 + row;
        if (grow < nrows) feat[(long)idx[grow] * HIDD + c] = o;
    }
}

// ---------------- rotation tables ----------------
// rfull: etype0 = r0/|r0|, etype1 = conj. user etypes [0,1]; item etypes [1,0].
__global__ void rot_kernel(const float* __restrict__ r_vec, float* __restrict__ fr_user,
                           float* __restrict__ fr_item)
{
    int p = threadIdx.x;
    if (p >= 32) return;
    float re0 = r_vec[p * 2], im0 = r_vec[p * 2 + 1];
    float n = sqrtf(re0 * re0 + im0 * im0);
    re0 /= n; im0 /= n;
    // user: fr[2]=I; fr[1]=rfull[1]=conj(r0); fr[0]=fr[1]*rfull[0]
    float u1re = re0, u1im = -im0;
    float u0re = u1re * re0 - u1im * im0;
    float u0im = u1re * im0 + u1im * re0;
    fr_user[0 * 64 + p * 2] = u0re; fr_user[0 * 64 + p * 2 + 1] = u0im;
    fr_user[1 * 64 + p * 2] = u1re; fr_user[1 * 64 + p * 2 + 1] = u1im;
    fr_user[2 * 64 + p * 2] = 1.f;  fr_user[2 * 64 + p * 2 + 1] = 0.f;
    // item: fr[1]=rfull[0]=r0; fr[0]=fr[1]*rfull[1]
    float i1re = re0, i1im = im0;
    float i0re = i1re * re0 - i1im * (-im0);
    float i0im = i1re * (-im0) + i1im * re0;
    fr_item[0 * 64 + p * 2] = i0re; fr_item[0 * 64 + p * 2 + 1] = i0im;
    fr_item[1 * 64 + p * 2] = i1re; fr_item[1 * 64 + p * 2 + 1] = i1im;
    fr_item[2 * 64 + p * 2] = 1.f;  fr_item[2 * 64 + p * 2 + 1] = 0.f;
}

// ---------------- metapath passes ----------------
__device__ __forceinline__ void atomicMaxFloat(float* addr, float val) {
    if (val >= 0.f) atomicMax((int*)addr, __float_as_int(val));
    else            atomicMin((unsigned int*)addr, __float_as_uint(val));
}

// pass1: rotated mean hidden -> head scores e; atomicMax into m (init 0xFFFFFFFF = NaN sentinel)
__global__ __launch_bounds__(256) void mp_pass1(
    const float* __restrict__ feat, const int* __restrict__ emi, const int* __restrict__ tgt,
    const float* __restrict__ attn, const float* __restrict__ fr,
    float* __restrict__ e_out, float* __restrict__ m)
{
    int tid = threadIdx.x;
    int p = tid & 31, iq = tid >> 5;
    int i = blockIdx.x * 8 + iq;
    if (i >= EEE) return;
    const float2* f2 = (const float2*)feat;
    const float2* fr2 = (const float2*)fr;
    const float2* at2 = (const float2*)attn;
    int n0 = emi[i * 3 + 0], n1 = emi[i * 3 + 1], n2 = emi[i * 3 + 2];
    float2 e0 = f2[n0 * 32 + p], e1 = f2[n1 * 32 + p], e2 = f2[n2 * 32 + p];
    float2 r0 = fr2[p], r1 = fr2[32 + p], r2 = fr2[64 + p];
    float re = (e0.x * r0.x - e0.y * r0.y) + (e1.x * r1.x - e1.y * r1.y) + (e2.x * r2.x - e2.y * r2.y);
    float im = (e0.x * r0.y + e0.y * r0.x) + (e1.x * r1.y + e1.y * r1.x) + (e2.x * r2.y + e2.y * r2.x);
    re *= (1.f / 3.f); im *= (1.f / 3.f);
    float2 at = at2[p];
    float part = re * at.x + im * at.y;
    part += __shfl_xor(part, 1);
    part += __shfl_xor(part, 2);
    float ev = part >= 0.f ? part : 0.01f * part;   // leaky_relu 0.01
    if ((p & 3) == 0) {
        int h = p >> 2;
        e_out[i * 8 + h] = ev;
        atomicMaxFloat(&m[tgt[i] * 8 + h], ev);
    }
}

// finalize m: non-finite (empty segment sentinel) -> 0
__global__ void finalize_m(float* __restrict__ m) {
    int i = blockIdx.x * 256 + threadIdx.x;
    if (i < BBB * 8) {
        unsigned u = __float_as_uint(m[i]);
        if ((u & 0x7f800000u) == 0x7f800000u) m[i] = 0.f;
    }
}

// pass3: a = exp(e - m[tgt]); segment-sum s
__global__ void mp_pass3(const int* __restrict__ tgt, const float* __restrict__ m,
                         float* __restrict__ ea, float* __restrict__ s)
{
    long idx = (long)blockIdx.x * 256 + threadIdx.x;
    if (idx >= (long)EEE * 8) return;
    int i = (int)(idx >> 3); int h = (int)(idx & 7);
    int t = tgt[i];
    float a = expf(ea[idx] - m[t * 8 + h]);
    ea[idx] = a;
    atomicAdd(&s[t * 8 + h], a);
}

// pass4: re-gather + rotate, scatter w*eft into ret
__global__ __launch_bounds__(256) void mp_pass4(
    const float* __restrict__ feat, const int* __restrict__ emi, const int* __restrict__ tgt,
    const float* __restrict__ fr, const float* __restrict__ ea, const float* __restrict__ s,
    float* __restrict__ ret)
{
    int tid = threadIdx.x;
    int p = tid & 31, iq = tid >> 5;
    int i = blockIdx.x * 8 + iq;
    if (i >= EEE) return;
    const float2* f2 = (const float2*)feat;
    const float2* fr2 = (const float2*)fr;
    int n0 = emi[i * 3 + 0], n1 = emi[i * 3 + 1], n2 = emi[i * 3 + 2];
    float2 e0 = f2[n0 * 32 + p], e1 = f2[n1 * 32 + p], e2 = f2[n2 * 32 + p];
    float2 r0 = fr2[p], r1 = fr2[32 + p], r2 = fr2[64 + p];
    float re = (e0.x * r0.x - e0.y * r0.y) + (e1.x * r1.x - e1.y * r1.y) + (e2.x * r2.x - e2.y * r2.y);
    float im = (e0.x * r0.y + e0.y * r0.x) + (e1.x * r1.y + e1.y * r1.x) + (e2.x * r2.y + e2.y * r2.x);
    re *= (1.f / 3.f); im *= (1.f / 3.f);
    int h = p >> 2;
    int t = tgt[i];
    float a = ea[i * 8 + h];
    float w = a / (s[t * 8 + h] + 1e-9f);
    atomicAdd(&ret[t * 64 + 2 * p], w * re);
    atomicAdd(&ret[t * 64 + 2 * p + 1], w * im);
}

__global__ void elu_kernel(float* __restrict__ ret, int n) {
    int i = blockIdx.x * 256 + threadIdx.x;
    if (i < n) { float v = ret[i]; ret[i] = v > 0.f ? v : expf(v) - 1.f; }
}

// ---------------- semantic attention scalar s[combo] = sum_b tanh(v@w1+b1)@w2 ----------------
__global__ __launch_bounds__(256) void sem_kernel(
    const float* __restrict__ ret,
    const float* __restrict__ su_w1, const float* __restrict__ su_b1, const float* __restrict__ su_w2,
    const float* __restrict__ si_w1, const float* __restrict__ si_b1, const float* __restrict__ si_w2,
    float* __restrict__ s_acc)
{
    int combo = blockIdx.x & 3;
    int wid = threadIdx.x >> 6, lane = threadIdx.x & 63;
    const float* w1 = combo < 2 ? su_w1 : si_w1;
    const float* b1 = combo < 2 ? su_b1 : si_b1;
    const float* w2 = combo < 2 ? su_w2 : si_w2;
    const float* out = ret + (long)combo * BBB * HIDD;
    int widx = (blockIdx.x >> 2) * 4 + wid; // 0..255 per combo
    float total = 0.f;
    for (int j = 0; j < 32; j++) {
        int b = widx + 256 * j;
        float v = out[(long)b * HIDD + lane];
        float a0 = b1[lane], a1 = b1[lane + 64];
        for (int k = 0; k < 64; k++) {
            float vk = __shfl(v, k);
            a0 = fmaf(vk, w1[k * AVV + lane], a0);
            a1 = fmaf(vk, w1[k * AVV + lane + 64], a1);
        }
        total += tanhf(a0) * w2[lane] + tanhf(a1) * w2[lane + 64];
    }
    for (int off = 32; off; off >>= 1) total += __shfl_xor(total, off);
    __shared__ float red[4];
    if (lane == 0) red[wid] = total;
    __syncthreads();
    if (threadIdx.x == 0) atomicAdd(&s_acc[combo], red[0] + red[1] + red[2] + red[3]);
}

__global__ void beta_kernel(const float* __restrict__ s_acc, float* __restrict__ beta) {
    if (threadIdx.x == 0) {
        float s0 = s_acc[0] / BBB, s1 = s_acc[1] / BBB;
        float s2 = s_acc[2] / BBB, s3 = s_acc[3] / BBB;
        float mu = fmaxf(s0, s1);
        float e0 = expf(s0 - mu), e1 = expf(s1 - mu);
        beta[0] = e0 / (e0 + e1); beta[1] = e1 / (e0 + e1);
        float mi = fmaxf(s2, s3);
        float f0 = expf(s2 - mi), f1 = expf(s3 - mi);
        beta[2] = f0 / (f0 + f1); beta[3] = f1 / (f0 + f1);
    }
}

// ---------------- final: x = h_user*h_item; relu(x@cw1+cb1)@cw2 -> softmax ----------------
__global__ __launch_bounds__(256) void final_kernel(
    const float* __restrict__ ret, const float* __restrict__ beta,
    const float* __restrict__ cw1, const float* __restrict__ cb1, const float* __restrict__ cw2,
    float* __restrict__ outp)
{
    int wid = threadIdx.x >> 6, lane = threadIdx.x & 63;
    int b = blockIdx.x * 4 + wid;
    if (b >= BBB) return;
    float hu = beta[0] * ret[(long)0 * BBB * HIDD + (long)b * HIDD + lane]
             + beta[1] * ret[(long)1 * BBB * HIDD + (long)b * HIDD + lane];
    float hi = beta[2] * ret[(long)2 * BBB * HIDD + (long)b * HIDD + lane]
             + beta[3] * ret[(long)3 * BBB * HIDD + (long)b * HIDD + lane];
    float x = hu * hi;
    float a0 = cb1[lane], a1 = cb1[lane + 64];
    for (int k = 0; k < 64; k++) {
        float vk = __shfl(x, k);
        a0 = fmaf(vk, cw1[k * CHH + lane], a0);
        a1 = fmaf(vk, cw1[k * CHH + lane + 64], a1);
    }
    a0 = fmaxf(a0, 0.f); a1 = fmaxf(a1, 0.f);
    float p0 = a0 * cw2[lane * 2] + a1 * cw2[(lane + 64) * 2];
    float p1 = a0 * cw2[lane * 2 + 1] + a1 * cw2[(lane + 64) * 2 + 1];
    for (int off = 32; off; off >>= 1) { p0 += __shfl_xor(p0, off); p1 += __shfl_xor(p1, off); }
    if (lane == 0) {
        float mx = fmaxf(p0, p1);
        float q0 = expf(p0 - mx), q1 = expf(p1 - mx);
        float d = q0 + q1;
        outp[b * 2] = q0 / d;
        outp[b * 2 + 1] = q1 / d;
    }
}

extern "C" void kernel_launch(void* const* d_in, const int* in_sizes, int n_in,
                              void* d_out, int out_size, void* d_ws, size_t ws_size,
                              hipStream_t stream)
{
    const float* feats0 = (const float*)d_in[0];
    const float* feats1 = (const float*)d_in[1];
    const float* t0_pw = (const float*)d_in[2];
    const float* t0_pb = (const float*)d_in[3];
    const float* t0_w2 = (const float*)d_in[4];
    const float* t0_b2 = (const float*)d_in[5];
    const float* t0_g  = (const float*)d_in[6];
    const float* t0_be = (const float*)d_in[7];
    const float* t1_pw = (const float*)d_in[8];
    const float* t1_pb = (const float*)d_in[9];
    const float* t1_w2 = (const float*)d_in[10];
    const float* t1_b2 = (const float*)d_in[11];
    const float* t1_g  = (const float*)d_in[12];
    const float* t1_be = (const float*)d_in[13];
    const float* r_vec = (const float*)d_in[14];
    const float* attn_user = (const float*)d_in[15];
    const float* attn_item = (const float*)d_in[16];
    const float* su_w1 = (const float*)d_in[17];
    const float* su_b1 = (const float*)d_in[18];
    const float* su_w2 = (const float*)d_in[19];
    const float* si_w1 = (const float*)d_in[20];
    const float* si_b1 = (const float*)d_in[21];
    const float* si_w2 = (const float*)d_in[22];
    const float* cw1 = (const float*)d_in[23];
    const float* cb1 = (const float*)d_in[24];
    const float* cw2 = (const float*)d_in[25];
    const int* idx0 = (const int*)d_in[26];
    const int* idx1 = (const int*)d_in[27];
    const int* emi_user = (const int*)d_in[28];
    const int* tgt_user = (const int*)d_in[29];
    const int* emi_item = (const int*)d_in[30];
    const int* tgt_item = (const int*)d_in[31];
    float* outp = (float*)d_out;

    // workspace layout (256B aligned)
    char* ws = (char*)d_ws;
    float* feat    = (float*)(ws + 0);                        // 40000*64*4 = 10,240,000
    float* fr_user = (float*)(ws + 10240000);                 // 768 B
    float* fr_item = (float*)(ws + 10240768);                 // 768 B
    float* s_acc   = (float*)(ws + 10241536);                 // 16 B
    float* beta    = (float*)(ws + 10241552);                 // 16 B
    float* m_buf   = (float*)(ws + 10241792);                 // 65536*4 = 262144
    float* s_buf   = (float*)(ws + 10503936);                 // 262144
    float* ea_buf  = (float*)(ws + 10766080);                 // 200000*8*4 = 6,400,000
    float* ret_buf = (float*)(ws + 17166080);                 // 4*8192*64*4 = 8,388,608
    // total ~25.6 MB

    // towers -> feat table
    tower_kernel<<<(NN0 + 63) / 64, 256, 0, stream>>>(feats0, t0_pw, t0_pb, t0_w2, t0_b2,
                                                      t0_g, t0_be, idx0, feat, NN0);
    tower_kernel<<<(NN1 + 63) / 64, 256, 0, stream>>>(feats1, t1_pw, t1_pb, t1_w2, t1_b2,
                                                      t1_g, t1_be, idx1, feat, NN1);
    rot_kernel<<<1, 32, 0, stream>>>(r_vec, fr_user, fr_item);

    hipMemsetAsync(ret_buf, 0, (size_t)4 * BBB * HIDD * sizeof(float), stream);

    for (int side = 0; side < 2; side++) {
        const int* emi_all = side == 0 ? emi_user : emi_item;
        const int* tgt_all = side == 0 ? tgt_user : tgt_item;
        const float* attn  = side == 0 ? attn_user : attn_item;
        const float* fr    = side == 0 ? fr_user : fr_item;
        for (int pth = 0; pth < 2; pth++) {
            const int* emi = emi_all + (long)pth * EEE * 3;
            const int* tgt = tgt_all + (long)pth * EEE;
            float* retp = ret_buf + (long)(side * 2 + pth) * BBB * HIDD;
            hipMemsetAsync(m_buf, 0xFF, BBB * 8 * sizeof(float), stream); // NaN sentinel
            hipMemsetAsync(s_buf, 0, BBB * 8 * sizeof(float), stream);
            mp_pass1<<<EEE / 8, 256, 0, stream>>>(feat, emi, tgt, attn + pth * 64, fr, ea_buf, m_buf);
            finalize_m<<<(BBB * 8 + 255) / 256, 256, 0, stream>>>(m_buf);
            mp_pass3<<<(EEE * 8 + 255) / 256, 256, 0, stream>>>(tgt, m_buf, ea_buf, s_buf);
            mp_pass4<<<EEE / 8, 256, 0, stream>>>(feat, emi, tgt, fr, ea_buf, s_buf, retp);
        }
    }

    elu_kernel<<<(4 * BBB * HIDD + 255) / 256, 256, 0, stream>>>(ret_buf, 4 * BBB * HIDD);

    hipMemsetAsync(s_acc, 0, 4 * sizeof(float), stream);
    sem_kernel<<<256, 256, 0, stream>>>(ret_buf, su_w1, su_b1, su_w2, si_w1, si_b1, si_w2, s_acc);
    beta_kernel<<<1, 64, 0, stream>>>(s_acc, beta);
    final_kernel<<<BBB / 4, 256, 0, stream>>>(ret_buf, beta, cw1, cb1, cw2, outp);
}

// Round 2
// 611.828 us; speedup vs baseline: 2.1740x; 2.1740x over previous
//
#include <hip/hip_runtime.h>
#include <math.h>

// MAGNN link prediction forward — fp32 throughout.
#define NN0 20000
#define NN1 20000
#define NTOT 40000
#define FF0 512
#define HIDD 64
#define EEE 200000
#define BBB 8192
#define AVV 128
#define CHH 128

// ---------------- tower: Linear(512->64) + GELU + Linear(64->64) + residual + LN ----------------
// 64 rows/block, 256 threads, 4x4 register tile per thread (VALU-bound inner loop).
__global__ __launch_bounds__(256) void tower_kernel(
    const float* __restrict__ x, const float* __restrict__ pw, const float* __restrict__ pb,
    const float* __restrict__ w2, const float* __restrict__ b2,
    const float* __restrict__ g, const float* __restrict__ be,
    const int* __restrict__ idx, float* __restrict__ feat, int nrows)
{
    __shared__ float xs[64][68];   // rows x k-chunk (GEMM1), reused as y rows x cols for LN
    __shared__ float wsh[64][64];  // k x col (pw chunk, then w2)
    __shared__ float hs[64][68];   // gelu output rows x k
    int tid = threadIdx.x;
    int ct = tid & 15, rt = tid >> 4;      // cols 4ct..4ct+3, rows 4rt..4rt+3
    int row0 = blockIdx.x * 64;

    float acc[4][4];
#pragma unroll
    for (int j = 0; j < 4; j++)
#pragma unroll
        for (int i = 0; i < 4; i++) acc[j][i] = 0.f;

    for (int k0 = 0; k0 < FF0; k0 += 64) {
        // stage x tile 64 rows x 64 k
        for (int li = tid; li < 1024; li += 256) {
            int r = li >> 4, k4 = (li & 15) * 4;
            float4 v = make_float4(0.f, 0.f, 0.f, 0.f);
            int gr = row0 + r;
            if (gr < nrows) v = *(const float4*)&x[(long)gr * FF0 + k0 + k4];
            *(float4*)&xs[r][k4] = v;
        }
        // stage pw chunk 64 k x 64 col (contiguous 16KB)
        const float4* pw4 = (const float4*)(pw + k0 * 64);
        for (int li = tid; li < 1024; li += 256) {
            float4 v = pw4[li];
            *(float4*)&wsh[li >> 4][(li & 15) * 4] = v;
        }
        __syncthreads();
        for (int k = 0; k < 64; k += 4) {
            float4 xv[4];
#pragma unroll
            for (int j = 0; j < 4; j++) xv[j] = *(const float4*)&xs[4 * rt + j][k];
#pragma unroll
            for (int kk = 0; kk < 4; kk++) {
                float4 wv = *(const float4*)&wsh[k + kk][4 * ct];
#pragma unroll
                for (int j = 0; j < 4; j++) {
                    float xx = kk == 0 ? xv[j].x : kk == 1 ? xv[j].y : kk == 2 ? xv[j].z : xv[j].w;
                    acc[j][0] = fmaf(xx, wv.x, acc[j][0]);
                    acc[j][1] = fmaf(xx, wv.y, acc[j][1]);
                    acc[j][2] = fmaf(xx, wv.z, acc[j][2]);
                    acc[j][3] = fmaf(xx, wv.w, acc[j][3]);
                }
            }
        }
        __syncthreads();
    }

    // z = acc + pb; h = gelu(z) -> hs
    float4 pbv = *(const float4*)&pb[4 * ct];
    float z[4][4];
#pragma unroll
    for (int j = 0; j < 4; j++) {
        z[j][0] = acc[j][0] + pbv.x; z[j][1] = acc[j][1] + pbv.y;
        z[j][2] = acc[j][2] + pbv.z; z[j][3] = acc[j][3] + pbv.w;
        float4 hv;
        hv.x = 0.5f * z[j][0] * (1.f + erff(z[j][0] * 0.70710678118654752f));
        hv.y = 0.5f * z[j][1] * (1.f + erff(z[j][1] * 0.70710678118654752f));
        hv.z = 0.5f * z[j][2] * (1.f + erff(z[j][2] * 0.70710678118654752f));
        hv.w = 0.5f * z[j][3] * (1.f + erff(z[j][3] * 0.70710678118654752f));
        *(float4*)&hs[4 * rt + j][4 * ct] = hv;
    }
    // stage w2 into wsh (GEMM1 done reading it: loop ended with __syncthreads)
    const float4* w24 = (const float4*)w2;
    for (int li = tid; li < 1024; li += 256) {
        float4 v = w24[li];
        *(float4*)&wsh[li >> 4][(li & 15) * 4] = v;
    }
    __syncthreads();

    // GEMM2: y = h@w2 + b2 + z
    float4 b2v = *(const float4*)&b2[4 * ct];
    float acc2[4][4];
#pragma unroll
    for (int j = 0; j < 4; j++) {
        acc2[j][0] = z[j][0] + b2v.x; acc2[j][1] = z[j][1] + b2v.y;
        acc2[j][2] = z[j][2] + b2v.z; acc2[j][3] = z[j][3] + b2v.w;
    }
    for (int k = 0; k < 64; k += 4) {
        float4 xv[4];
#pragma unroll
        for (int j = 0; j < 4; j++) xv[j] = *(const float4*)&hs[4 * rt + j][k];
#pragma unroll
        for (int kk = 0; kk < 4; kk++) {
            float4 wv = *(const float4*)&wsh[k + kk][4 * ct];
#pragma unroll
            for (int j = 0; j < 4; j++) {
                float xx = kk == 0 ? xv[j].x : kk == 1 ? xv[j].y : kk == 2 ? xv[j].z : xv[j].w;
                acc2[j][0] = fmaf(xx, wv.x, acc2[j][0]);
                acc2[j][1] = fmaf(xx, wv.y, acc2[j][1]);
                acc2[j][2] = fmaf(xx, wv.z, acc2[j][2]);
                acc2[j][3] = fmaf(xx, wv.w, acc2[j][3]);
            }
        }
    }
    __syncthreads();
    // write y rows into xs (free since GEMM1 done) for LN remap
#pragma unroll
    for (int j = 0; j < 4; j++)
        *(float4*)&xs[4 * rt + j][4 * ct] = make_float4(acc2[j][0], acc2[j][1], acc2[j][2], acc2[j][3]);
    __syncthreads();

    // LayerNorm: lane = col, 4 waves x 16 rows
    int lane = tid & 63, wid = tid >> 6;
    float gc = g[lane], bec = be[lane];
    for (int rr = wid; rr < 64; rr += 4) {
        float y = xs[rr][lane];
        float mu = y;
        for (int off = 32; off; off >>= 1) mu += __shfl_xor(mu, off);
        mu *= (1.f / 64.f);
        float d = y - mu;
        float var = d * d;
        for (int off = 32; off; off >>= 1) var += __shfl_xor(var, off);
        var *= (1.f / 64.f);
        float o = d / sqrtf(var + 1e-5f) * gc + bec;
        int grow = row0 + rr;
        if (grow < nrows) feat[(long)idx[grow] * HIDD + lane] = o;
    }
}

// ---------------- rotation tables ----------------
__global__ void rot_kernel(const float* __restrict__ r_vec, float* __restrict__ fr_user,
                           float* __restrict__ fr_item)
{
    int p = threadIdx.x;
    if (p >= 32) return;
    float re0 = r_vec[p * 2], im0 = r_vec[p * 2 + 1];
    float n = sqrtf(re0 * re0 + im0 * im0);
    re0 /= n; im0 /= n;
    // user: fr[2]=I; fr[1]=conj(r0); fr[0]=fr[1]*r0
    float u1re = re0, u1im = -im0;
    float u0re = u1re * re0 - u1im * im0;
    float u0im = u1re * im0 + u1im * re0;
    fr_user[0 * 64 + p * 2] = u0re; fr_user[0 * 64 + p * 2 + 1] = u0im;
    fr_user[1 * 64 + p * 2] = u1re; fr_user[1 * 64 + p * 2 + 1] = u1im;
    fr_user[2 * 64 + p * 2] = 1.f;  fr_user[2 * 64 + p * 2 + 1] = 0.f;
    // item: fr[1]=r0; fr[0]=fr[1]*conj(r0)
    float i1re = re0, i1im = im0;
    float i0re = i1re * re0 - i1im * (-im0);
    float i0im = i1re * (-im0) + i1im * re0;
    fr_item[0 * 64 + p * 2] = i0re; fr_item[0 * 64 + p * 2 + 1] = i0im;
    fr_item[1 * 64 + p * 2] = i1re; fr_item[1 * 64 + p * 2 + 1] = i1im;
    fr_item[2 * 64 + p * 2] = 1.f;  fr_item[2 * 64 + p * 2 + 1] = 0.f;
}

// ---------------- CSR build ----------------
__global__ void hist_kernel(const int* __restrict__ tgt_user, const int* __restrict__ tgt_item,
                            int* __restrict__ cnt)
{
    int combo = blockIdx.y;
    const int* tgt = (combo < 2 ? tgt_user : tgt_item) + (long)(combo & 1) * EEE;
    int i = blockIdx.x * 256 + threadIdx.x;
    if (i < EEE) atomicAdd(&cnt[combo * BBB + tgt[i]], 1);
}

__global__ __launch_bounds__(256) void scan_kernel(const int* __restrict__ cnt, int* __restrict__ offs)
{
    int pth = blockIdx.x;
    const int* c = cnt + pth * BBB;
    int* o = offs + pth * (BBB + 1);
    __shared__ int part[256];
    int tid = threadIdx.x;
    int base = tid * 32;
    int local[32];
    int sum = 0;
    for (int j = 0; j < 32; j++) { local[j] = sum; sum += c[base + j]; }
    part[tid] = sum;
    __syncthreads();
    for (int d = 1; d < 256; d <<= 1) {
        int v = (tid >= d) ? part[tid - d] : 0;
        __syncthreads();
        part[tid] += v;
        __syncthreads();
    }
    int pre = (tid == 0) ? 0 : part[tid - 1];
    for (int j = 0; j < 32; j++) o[base + j] = pre + local[j];
    if (tid == 255) o[BBB] = pre + sum;
}

__global__ void scatter_kernel(const int* __restrict__ tgt_user, const int* __restrict__ tgt_item,
                               const int* __restrict__ offs, int* __restrict__ cur, int* __restrict__ perm)
{
    int combo = blockIdx.y;
    const int* tgt = (combo < 2 ? tgt_user : tgt_item) + (long)(combo & 1) * EEE;
    int i = blockIdx.x * 256 + threadIdx.x;
    if (i < EEE) {
        int t = tgt[i];
        int pos = offs[combo * (BBB + 1) + t] + atomicAdd(&cur[combo * BBB + t], 1);
        perm[(long)combo * EEE + pos] = i;
    }
}

// ---------------- flash metapath: gather + rotate + attention + online softmax + ELU ----------------
// one 64-lane wave per (target, combo); no atomics.
__global__ __launch_bounds__(256) void flash_mp(
    const float* __restrict__ feat,
    const int* __restrict__ emi_user, const int* __restrict__ emi_item,
    const int* __restrict__ offs, const int* __restrict__ perm,
    const float* __restrict__ attn_user, const float* __restrict__ attn_item,
    const float* __restrict__ fr_user, const float* __restrict__ fr_item,
    float* __restrict__ ret)
{
    int combo = blockIdx.y;
    int wid = threadIdx.x >> 6, lane = threadIdx.x & 63;
    int t = blockIdx.x * 4 + wid;
    const int* emi = (combo < 2 ? emi_user : emi_item) + (long)(combo & 1) * EEE * 3;
    const float* attn = (combo < 2 ? attn_user : attn_item) + (combo & 1) * 64;
    const float* fr = (combo < 2) ? fr_user : fr_item;
    const float2* f2 = (const float2*)feat;
    int p = lane >> 1, isim = lane & 1;
    float r0x = fr[2 * p], r0y = fr[2 * p + 1];
    float r1x = fr[64 + 2 * p], r1y = fr[64 + 2 * p + 1];
    float r2x = fr[128 + 2 * p], r2y = fr[128 + 2 * p + 1];
    float av = attn[lane];
    int beg = offs[combo * (BBB + 1) + t], end = offs[combo * (BBB + 1) + t + 1];
    const int* pm = perm + (long)combo * EEE;

    float m = -3.4e38f, s = 0.f, O = 0.f;
    // 1-deep pipeline: prefetch next instance's node ids + feature pairs
    float2 P0, P1, P2;
    if (beg < end) {
        int i0 = pm[beg];
        int a0 = emi[(long)i0 * 3], a1 = emi[(long)i0 * 3 + 1], a2 = emi[(long)i0 * 3 + 2];
        P0 = f2[a0 * 32 + p]; P1 = f2[a1 * 32 + p]; P2 = f2[a2 * 32 + p];
    }
    for (int j = beg; j < end; j++) {
        float2 e0 = P0, e1 = P1, e2 = P2;
        if (j + 1 < end) {
            int i1 = pm[j + 1];
            int b0 = emi[(long)i1 * 3], b1 = emi[(long)i1 * 3 + 1], b2n = emi[(long)i1 * 3 + 2];
            P0 = f2[b0 * 32 + p]; P1 = f2[b1 * 32 + p]; P2 = f2[b2n * 32 + p];
        }
        float re = (e0.x * r0x - e0.y * r0y) + (e1.x * r1x - e1.y * r1y) + (e2.x * r2x - e2.y * r2y);
        float im = (e0.x * r0y + e0.y * r0x) + (e1.x * r1y + e1.y * r1x) + (e2.x * r2y + e2.y * r2x);
        float val = (isim ? im : re) * (1.f / 3.f);
        float ve = val * av;
        ve += __shfl_xor(ve, 1);
        ve += __shfl_xor(ve, 2);
        ve += __shfl_xor(ve, 4);
        float e = ve > 0.f ? ve : 0.01f * ve;   // leaky_relu
        float mn = fmaxf(m, e);
        float alpha = expf(m - mn);
        float w = expf(e - mn);
        s = s * alpha + w;
        O = O * alpha + w * val;
        m = mn;
    }
    float v = O / (s + 1e-9f);
    v = v > 0.f ? v : expf(v) - 1.f;            // ELU
    ret[(long)combo * BBB * HIDD + (long)t * HIDD + lane] = v;
}

// ---------------- semantic attention scalar ----------------
__global__ __launch_bounds__(256) void sem_kernel(
    const float* __restrict__ ret,
    const float* __restrict__ su_w1, const float* __restrict__ su_b1, const float* __restrict__ su_w2,
    const float* __restrict__ si_w1, const float* __restrict__ si_b1, const float* __restrict__ si_w2,
    float* __restrict__ s_acc)
{
    int combo = blockIdx.x & 3;
    int wid = threadIdx.x >> 6, lane = threadIdx.x & 63;
    const float* w1 = combo < 2 ? su_w1 : si_w1;
    const float* b1 = combo < 2 ? su_b1 : si_b1;
    const float* w2 = combo < 2 ? su_w2 : si_w2;
    const float* out = ret + (long)combo * BBB * HIDD;
    int widx = (blockIdx.x >> 2) * 4 + wid;
    float total = 0.f;
    for (int j = 0; j < 32; j++) {
        int b = widx + 256 * j;
        float v = out[(long)b * HIDD + lane];
        float a0 = b1[lane], a1 = b1[lane + 64];
        for (int k = 0; k < 64; k++) {
            float vk = __shfl(v, k);
            a0 = fmaf(vk, w1[k * AVV + lane], a0);
            a1 = fmaf(vk, w1[k * AVV + lane + 64], a1);
        }
        total += tanhf(a0) * w2[lane] + tanhf(a1) * w2[lane + 64];
    }
    for (int off = 32; off; off >>= 1) total += __shfl_xor(total, off);
    __shared__ float red[4];
    if (lane == 0) red[wid] = total;
    __syncthreads();
    if (threadIdx.x == 0) atomicAdd(&s_acc[combo], red[0] + red[1] + red[2] + red[3]);
}

__global__ void beta_kernel(const float* __restrict__ s_acc, float* __restrict__ beta) {
    if (threadIdx.x == 0) {
        float s0 = s_acc[0] / BBB, s1 = s_acc[1] / BBB;
        float s2 = s_acc[2] / BBB, s3 = s_acc[3] / BBB;
        float mu = fmaxf(s0, s1);
        float e0 = expf(s0 - mu), e1 = expf(s1 - mu);
        beta[0] = e0 / (e0 + e1); beta[1] = e1 / (e0 + e1);
        float mi = fmaxf(s2, s3);
        float f0 = expf(s2 - mi), f1 = expf(s3 - mi);
        beta[2] = f0 / (f0 + f1); beta[3] = f1 / (f0 + f1);
    }
}

// ---------------- final product MLP + softmax ----------------
__global__ __launch_bounds__(256) void final_kernel(
    const float* __restrict__ ret, const float* __restrict__ beta,
    const float* __restrict__ cw1, const float* __restrict__ cb1, const float* __restrict__ cw2,
    float* __restrict__ outp)
{
    int wid = threadIdx.x >> 6, lane = threadIdx.x & 63;
    int b = blockIdx.x * 4 + wid;
    if (b >= BBB) return;
    float hu = beta[0] * ret[(long)0 * BBB * HIDD + (long)b * HIDD + lane]
             + beta[1] * ret[(long)1 * BBB * HIDD + (long)b * HIDD + lane];
    float hi = beta[2] * ret[(long)2 * BBB * HIDD + (long)b * HIDD + lane]
             + beta[3] * ret[(long)3 * BBB * HIDD + (long)b * HIDD + lane];
    float x = hu * hi;
    float a0 = cb1[lane], a1 = cb1[lane + 64];
    for (int k = 0; k < 64; k++) {
        float vk = __shfl(x, k);
        a0 = fmaf(vk, cw1[k * CHH + lane], a0);
        a1 = fmaf(vk, cw1[k * CHH + lane + 64], a1);
    }
    a0 = fmaxf(a0, 0.f); a1 = fmaxf(a1, 0.f);
    float p0 = a0 * cw2[lane * 2] + a1 * cw2[(lane + 64) * 2];
    float p1 = a0 * cw2[lane * 2 + 1] + a1 * cw2[(lane + 64) * 2 + 1];
    for (int off = 32; off; off >>= 1) { p0 += __shfl_xor(p0, off); p1 += __shfl_xor(p1, off); }
    if (lane == 0) {
        float mx = fmaxf(p0, p1);
        float q0 = expf(p0 - mx), q1 = expf(p1 - mx);
        float d = q0 + q1;
        outp[b * 2] = q0 / d;
        outp[b * 2 + 1] = q1 / d;
    }
}

extern "C" void kernel_launch(void* const* d_in, const int* in_sizes, int n_in,
                              void* d_out, int out_size, void* d_ws, size_t ws_size,
                              hipStream_t stream)
{
    const float* feats0 = (const float*)d_in[0];
    const float* feats1 = (const float*)d_in[1];
    const float* t0_pw = (const float*)d_in[2];
    const float* t0_pb = (const float*)d_in[3];
    const float* t0_w2 = (const float*)d_in[4];
    const float* t0_b2 = (const float*)d_in[5];
    const float* t0_g  = (const float*)d_in[6];
    const float* t0_be = (const float*)d_in[7];
    const float* t1_pw = (const float*)d_in[8];
    const float* t1_pb = (const float*)d_in[9];
    const float* t1_w2 = (const float*)d_in[10];
    const float* t1_b2 = (const float*)d_in[11];
    const float* t1_g  = (const float*)d_in[12];
    const float* t1_be = (const float*)d_in[13];
    const float* r_vec = (const float*)d_in[14];
    const float* attn_user = (const float*)d_in[15];
    const float* attn_item = (const float*)d_in[16];
    const float* su_w1 = (const float*)d_in[17];
    const float* su_b1 = (const float*)d_in[18];
    const float* su_w2 = (const float*)d_in[19];
    const float* si_w1 = (const float*)d_in[20];
    const float* si_b1 = (const float*)d_in[21];
    const float* si_w2 = (const float*)d_in[22];
    const float* cw1 = (const float*)d_in[23];
    const float* cb1 = (const float*)d_in[24];
    const float* cw2 = (const float*)d_in[25];
    const int* idx0 = (const int*)d_in[26];
    const int* idx1 = (const int*)d_in[27];
    const int* emi_user = (const int*)d_in[28];
    const int* tgt_user = (const int*)d_in[29];
    const int* emi_item = (const int*)d_in[30];
    const int* tgt_item = (const int*)d_in[31];
    float* outp = (float*)d_out;

    // workspace layout
    char* ws = (char*)d_ws;
    float* feat    = (float*)(ws + 0);              // 10,240,000
    float* fr_user = (float*)(ws + 10240000);       // 768
    float* fr_item = (float*)(ws + 10240768);       // 768
    float* s_acc   = (float*)(ws + 10241536);       // 16 (pad to 256)
    int*   cnt     = (int*)(ws + 10241792);         // 4*8192*4 = 131072
    int*   cur     = (int*)(ws + 10372864);         // 131072
    int*   offs    = (int*)(ws + 10503936);         // 4*8193*4 = 131088 (pad)
    int*   perm    = (int*)(ws + 10635264);         // 4*200000*4 = 3,200,000
    float* beta    = (float*)(ws + 13835264);       // 16 (pad to 256)
    float* ret_buf = (float*)(ws + 13835520);       // 4*8192*64*4 = 8,388,608
    // total 22,224,128 bytes

    // towers -> feat table
    tower_kernel<<<(NN0 + 63) / 64, 256, 0, stream>>>(feats0, t0_pw, t0_pb, t0_w2, t0_b2,
                                                      t0_g, t0_be, idx0, feat, NN0);
    tower_kernel<<<(NN1 + 63) / 64, 256, 0, stream>>>(feats1, t1_pw, t1_pb, t1_w2, t1_b2,
                                                      t1_g, t1_be, idx1, feat, NN1);
    rot_kernel<<<1, 32, 0, stream>>>(r_vec, fr_user, fr_item);

    // CSR build (cnt + cur contiguous -> one memset)
    hipMemsetAsync(cnt, 0, 2 * 4 * BBB * sizeof(int), stream);
    hist_kernel<<<dim3((EEE + 255) / 256, 4), 256, 0, stream>>>(tgt_user, tgt_item, cnt);
    scan_kernel<<<4, 256, 0, stream>>>(cnt, offs);
    scatter_kernel<<<dim3((EEE + 255) / 256, 4), 256, 0, stream>>>(tgt_user, tgt_item, offs, cur, perm);

    // fused metapath aggregation
    flash_mp<<<dim3(BBB / 4, 4), 256, 0, stream>>>(feat, emi_user, emi_item, offs, perm,
                                                   attn_user, attn_item, fr_user, fr_item, ret_buf);

    // semantic attention + final MLP
    hipMemsetAsync(s_acc, 0, 4 * sizeof(float), stream);
    sem_kernel<<<256, 256, 0, stream>>>(ret_buf, su_w1, su_b1, su_w2, si_w1, si_b1, si_w2, s_acc);
    beta_kernel<<<1, 64, 0, stream>>>(s_acc, beta);
    final_kernel<<<BBB / 4, 256, 0, stream>>>(ret_buf, beta, cw1, cb1, cw2, outp);
}

// Round 3
// 545.576 us; speedup vs baseline: 2.4380x; 1.1214x over previous
//
#include <hip/hip_runtime.h>
#include <math.h>

// MAGNN link prediction forward — fp32 throughout.
#define NN0 20000
#define NN1 20000
#define NTOT 40000
#define FF0 512
#define HIDD 64
#define EEE 200000
#define BBB 8192
#define AVV 128
#define CHH 128

__device__ __forceinline__ float fast_tanh(float x) {
    // 1 - 2/(e^{2x}+1): NaN-free (e2=inf -> 1, e2=0 -> -1)
    float e2 = __expf(2.f * x);
    return 1.f - 2.f / (e2 + 1.f);
}

// ---------------- tower: Linear(512->64) + GELU + Linear(64->64) + residual + LN ----------------
__global__ __launch_bounds__(256) void tower_kernel(
    const float* __restrict__ x, const float* __restrict__ pw, const float* __restrict__ pb,
    const float* __restrict__ w2, const float* __restrict__ b2,
    const float* __restrict__ g, const float* __restrict__ be,
    const int* __restrict__ idx, float* __restrict__ feat, int nrows)
{
    __shared__ float xs[64][68];   // rows x k-chunk (GEMM1), reused as y rows x cols for LN
    __shared__ float wsh[64][64];  // k x col (pw chunk, then w2)
    __shared__ float hs[64][68];   // gelu output rows x k
    int tid = threadIdx.x;
    int ct = tid & 15, rt = tid >> 4;
    int row0 = blockIdx.x * 64;

    float acc[4][4];
#pragma unroll
    for (int j = 0; j < 4; j++)
#pragma unroll
        for (int i = 0; i < 4; i++) acc[j][i] = 0.f;

    for (int k0 = 0; k0 < FF0; k0 += 64) {
        for (int li = tid; li < 1024; li += 256) {
            int r = li >> 4, k4 = (li & 15) * 4;
            float4 v = make_float4(0.f, 0.f, 0.f, 0.f);
            int gr = row0 + r;
            if (gr < nrows) v = *(const float4*)&x[(long)gr * FF0 + k0 + k4];
            *(float4*)&xs[r][k4] = v;
        }
        const float4* pw4 = (const float4*)(pw + k0 * 64);
        for (int li = tid; li < 1024; li += 256) {
            float4 v = pw4[li];
            *(float4*)&wsh[li >> 4][(li & 15) * 4] = v;
        }
        __syncthreads();
        for (int k = 0; k < 64; k += 4) {
            float4 xv[4];
#pragma unroll
            for (int j = 0; j < 4; j++) xv[j] = *(const float4*)&xs[4 * rt + j][k];
#pragma unroll
            for (int kk = 0; kk < 4; kk++) {
                float4 wv = *(const float4*)&wsh[k + kk][4 * ct];
#pragma unroll
                for (int j = 0; j < 4; j++) {
                    float xx = kk == 0 ? xv[j].x : kk == 1 ? xv[j].y : kk == 2 ? xv[j].z : xv[j].w;
                    acc[j][0] = fmaf(xx, wv.x, acc[j][0]);
                    acc[j][1] = fmaf(xx, wv.y, acc[j][1]);
                    acc[j][2] = fmaf(xx, wv.z, acc[j][2]);
                    acc[j][3] = fmaf(xx, wv.w, acc[j][3]);
                }
            }
        }
        __syncthreads();
    }

    float4 pbv = *(const float4*)&pb[4 * ct];
    float z[4][4];
#pragma unroll
    for (int j = 0; j < 4; j++) {
        z[j][0] = acc[j][0] + pbv.x; z[j][1] = acc[j][1] + pbv.y;
        z[j][2] = acc[j][2] + pbv.z; z[j][3] = acc[j][3] + pbv.w;
        float4 hv;
        hv.x = 0.5f * z[j][0] * (1.f + erff(z[j][0] * 0.70710678118654752f));
        hv.y = 0.5f * z[j][1] * (1.f + erff(z[j][1] * 0.70710678118654752f));
        hv.z = 0.5f * z[j][2] * (1.f + erff(z[j][2] * 0.70710678118654752f));
        hv.w = 0.5f * z[j][3] * (1.f + erff(z[j][3] * 0.70710678118654752f));
        *(float4*)&hs[4 * rt + j][4 * ct] = hv;
    }
    const float4* w24 = (const float4*)w2;
    for (int li = tid; li < 1024; li += 256) {
        float4 v = w24[li];
        *(float4*)&wsh[li >> 4][(li & 15) * 4] = v;
    }
    __syncthreads();

    float4 b2v = *(const float4*)&b2[4 * ct];
    float acc2[4][4];
#pragma unroll
    for (int j = 0; j < 4; j++) {
        acc2[j][0] = z[j][0] + b2v.x; acc2[j][1] = z[j][1] + b2v.y;
        acc2[j][2] = z[j][2] + b2v.z; acc2[j][3] = z[j][3] + b2v.w;
    }
    for (int k = 0; k < 64; k += 4) {
        float4 xv[4];
#pragma unroll
        for (int j = 0; j < 4; j++) xv[j] = *(const float4*)&hs[4 * rt + j][k];
#pragma unroll
        for (int kk = 0; kk < 4; kk++) {
            float4 wv = *(const float4*)&wsh[k + kk][4 * ct];
#pragma unroll
            for (int j = 0; j < 4; j++) {
                float xx = kk == 0 ? xv[j].x : kk == 1 ? xv[j].y : kk == 2 ? xv[j].z : xv[j].w;
                acc2[j][0] = fmaf(xx, wv.x, acc2[j][0]);
                acc2[j][1] = fmaf(xx, wv.y, acc2[j][1]);
                acc2[j][2] = fmaf(xx, wv.z, acc2[j][2]);
                acc2[j][3] = fmaf(xx, wv.w, acc2[j][3]);
            }
        }
    }
    __syncthreads();
#pragma unroll
    for (int j = 0; j < 4; j++)
        *(float4*)&xs[4 * rt + j][4 * ct] = make_float4(acc2[j][0], acc2[j][1], acc2[j][2], acc2[j][3]);
    __syncthreads();

    int lane = tid & 63, wid = tid >> 6;
    float gc = g[lane], bec = be[lane];
    for (int rr = wid; rr < 64; rr += 4) {
        float y = xs[rr][lane];
        float mu = y;
        for (int off = 32; off; off >>= 1) mu += __shfl_xor(mu, off);
        mu *= (1.f / 64.f);
        float d = y - mu;
        float var = d * d;
        for (int off = 32; off; off >>= 1) var += __shfl_xor(var, off);
        var *= (1.f / 64.f);
        float o = d / sqrtf(var + 1e-5f) * gc + bec;
        int grow = row0 + rr;
        if (grow < nrows) feat[(long)idx[grow] * HIDD + lane] = o;
    }
}

// ---------------- rotation: only the middle node is rotated (pos0/pos2 are identity since |r|=1) ----
// rot2[0..31] = user (conj r0), rot2[32..63] = item (r0)
__global__ void rot_kernel(const float* __restrict__ r_vec, float2* __restrict__ rot2)
{
    int p = threadIdx.x;
    if (p >= 32) return;
    float re0 = r_vec[p * 2], im0 = r_vec[p * 2 + 1];
    float n = sqrtf(re0 * re0 + im0 * im0);
    re0 /= n; im0 /= n;
    rot2[p] = make_float2(re0, -im0);       // user: conj(r0)
    rot2[32 + p] = make_float2(re0, im0);   // item: r0
}

// ---------------- CSR build ----------------
__global__ void hist_kernel(const int* __restrict__ tgt_user, const int* __restrict__ tgt_item,
                            int* __restrict__ cnt)
{
    int combo = blockIdx.y;
    const int* tgt = (combo < 2 ? tgt_user : tgt_item) + (long)(combo & 1) * EEE;
    int i = blockIdx.x * 256 + threadIdx.x;
    if (i < EEE) atomicAdd(&cnt[combo * BBB + tgt[i]], 1);
}

__global__ __launch_bounds__(256) void scan_kernel(const int* __restrict__ cnt, int* __restrict__ offs)
{
    int pth = blockIdx.x;
    const int* c = cnt + pth * BBB;
    int* o = offs + pth * (BBB + 1);
    __shared__ int part[256];
    int tid = threadIdx.x;
    int base = tid * 32;
    int local[32];
    int sum = 0;
    for (int j = 0; j < 32; j++) { local[j] = sum; sum += c[base + j]; }
    part[tid] = sum;
    __syncthreads();
    for (int d = 1; d < 256; d <<= 1) {
        int v = (tid >= d) ? part[tid - d] : 0;
        __syncthreads();
        part[tid] += v;
        __syncthreads();
    }
    int pre = (tid == 0) ? 0 : part[tid - 1];
    for (int j = 0; j < 32; j++) o[base + j] = pre + local[j];
    if (tid == 255) o[BBB] = pre + sum;
}

__global__ void scatter_kernel(const int* __restrict__ tgt_user, const int* __restrict__ tgt_item,
                               const int* __restrict__ offs, int* __restrict__ cur, int* __restrict__ perm)
{
    int combo = blockIdx.y;
    const int* tgt = (combo < 2 ? tgt_user : tgt_item) + (long)(combo & 1) * EEE;
    int i = blockIdx.x * 256 + threadIdx.x;
    if (i < EEE) {
        int t = tgt[i];
        int pos = offs[combo * (BBB + 1) + t] + atomicAdd(&cur[combo * BBB + t], 1);
        perm[(long)combo * EEE + pos] = i;
    }
}

// ---------------- flash metapath + fused semantic-score epilogue ----------------
// one 64-lane wave per (target, combo); each lane owns a complex pair; the two
// 32-lane halves process 2 instances per iteration with shared online-softmax state.
__global__ __launch_bounds__(256) void flash_mp(
    const float* __restrict__ feat,
    const int* __restrict__ emi_user, const int* __restrict__ emi_item,
    const int* __restrict__ offs, const int* __restrict__ perm,
    const float* __restrict__ attn_user, const float* __restrict__ attn_item,
    const float2* __restrict__ rot2,
    const float* __restrict__ su_w1, const float* __restrict__ su_b1, const float* __restrict__ su_w2,
    const float* __restrict__ si_w1, const float* __restrict__ si_b1, const float* __restrict__ si_w2,
    float* __restrict__ s_acc, float* __restrict__ ret)
{
    int combo = blockIdx.y;
    int wid = threadIdx.x >> 6, lane = threadIdx.x & 63;
    int half = lane >> 5, p = lane & 31;
    int side = combo >> 1;
    const int* emi = (side == 0 ? emi_user : emi_item) + (long)(combo & 1) * EEE * 3;
    const float* attn = (side == 0 ? attn_user : attn_item) + (combo & 1) * 64;
    const float2* f2 = (const float2*)feat;
    float2 rv = rot2[side * 32 + p];
    float aRe = attn[2 * p], aIm = attn[2 * p + 1];
    int t = blockIdx.x * 4 + wid;
    int beg = offs[combo * (BBB + 1) + t], end = offs[combo * (BBB + 1) + t + 1];
    const int* pm = perm + (long)combo * EEE;
    int n = end - beg;

    float m = -3.4e38f, s = 0.f, Ox = 0.f, Oy = 0.f;
    // 1-deep pipeline
    float2 P0, P1, P2;
    if (n > 0) {
        int idc = beg + half; if (idc >= end) idc = end - 1;
        int i0 = pm[idc];
        P0 = f2[emi[3 * i0] * 32 + p];
        P1 = f2[emi[3 * i0 + 1] * 32 + p];
        P2 = f2[emi[3 * i0 + 2] * 32 + p];
    }
    for (int it = 0; it < n; it += 2) {
        float2 e0 = P0, e1 = P1, e2 = P2;
        bool valid = (it + half) < n;
        if (it + 2 < n) {
            int idc = beg + it + 2 + half; if (idc >= end) idc = end - 1;
            int i1 = pm[idc];
            P0 = f2[emi[3 * i1] * 32 + p];
            P1 = f2[emi[3 * i1 + 1] * 32 + p];
            P2 = f2[emi[3 * i1 + 2] * 32 + p];
        }
        float re = (e0.x + e2.x + e1.x * rv.x - e1.y * rv.y) * (1.f / 3.f);
        float im = (e0.y + e2.y + e1.x * rv.y + e1.y * rv.x) * (1.f / 3.f);
        float part = re * aRe + im * aIm;
        part += __shfl_xor(part, 1);
        part += __shfl_xor(part, 2);
        float e = part > 0.f ? part : 0.01f * part;   // leaky_relu
        if (!valid) e = -3.4e38f;
        float eo = __shfl_xor(e, 32);
        float mn = fmaxf(m, fmaxf(e, eo));
        float alpha = __expf(m - mn);
        float wS = __expf(e - mn);
        float wO = __expf(eo - mn);
        s = s * alpha + wS + wO;
        Ox = Ox * alpha + wS * re;
        Oy = Oy * alpha + wS * im;
        m = mn;
    }
    // combine halves (both halves end with identical v)
    float sx = __shfl_xor(Ox, 32), sy = __shfl_xor(Oy, 32);
    float inv = 1.f / (s + 1e-9f);
    float vx = (Ox + sx) * inv, vy = (Oy + sy) * inv;
    vx = vx > 0.f ? vx : __expf(vx) - 1.f;   // ELU
    vy = vy > 0.f ? vy : __expf(vy) - 1.f;
    if (half == 0)
        ((float2*)ret)[((long)combo * BBB + t) * 32 + p] = make_float2(vx, vy);

    // fused semantic score: tanh(v @ w1 + b1) @ w2, summed over rows
    const float* w1 = side == 0 ? su_w1 : si_w1;
    const float* b1 = side == 0 ? su_b1 : si_b1;
    const float* w2 = side == 0 ? su_w2 : si_w2;
    float a0 = b1[lane], a1 = b1[lane + 64];
    for (int k = 0; k < 64; k++) {
        float vk = __shfl((k & 1) ? vy : vx, k >> 1);
        a0 = fmaf(vk, w1[k * AVV + lane], a0);
        a1 = fmaf(vk, w1[k * AVV + lane + 64], a1);
    }
    float total = fast_tanh(a0) * w2[lane] + fast_tanh(a1) * w2[lane + 64];
    for (int off = 32; off; off >>= 1) total += __shfl_xor(total, off);
    __shared__ float red[4];
    if (lane == 0) red[wid] = total;
    __syncthreads();
    if (threadIdx.x == 0) atomicAdd(&s_acc[combo], red[0] + red[1] + red[2] + red[3]);
}

__global__ void beta_kernel(const float* __restrict__ s_acc, float* __restrict__ beta) {
    if (threadIdx.x == 0) {
        float s0 = s_acc[0] / BBB, s1 = s_acc[1] / BBB;
        float s2 = s_acc[2] / BBB, s3 = s_acc[3] / BBB;
        float mu = fmaxf(s0, s1);
        float e0 = __expf(s0 - mu), e1 = __expf(s1 - mu);
        beta[0] = e0 / (e0 + e1); beta[1] = e1 / (e0 + e1);
        float mi = fmaxf(s2, s3);
        float f0 = __expf(s2 - mi), f1 = __expf(s3 - mi);
        beta[2] = f0 / (f0 + f1); beta[3] = f1 / (f0 + f1);
    }
}

// ---------------- final product MLP + softmax ----------------
__global__ __launch_bounds__(256) void final_kernel(
    const float* __restrict__ ret, const float* __restrict__ beta,
    const float* __restrict__ cw1, const float* __restrict__ cb1, const float* __restrict__ cw2,
    float* __restrict__ outp)
{
    int wid = threadIdx.x >> 6, lane = threadIdx.x & 63;
    int b = blockIdx.x * 4 + wid;
    if (b >= BBB) return;
    float hu = beta[0] * ret[(long)0 * BBB * HIDD + (long)b * HIDD + lane]
             + beta[1] * ret[(long)1 * BBB * HIDD + (long)b * HIDD + lane];
    float hi = beta[2] * ret[(long)2 * BBB * HIDD + (long)b * HIDD + lane]
             + beta[3] * ret[(long)3 * BBB * HIDD + (long)b * HIDD + lane];
    float x = hu * hi;
    float a0 = cb1[lane], a1 = cb1[lane + 64];
    for (int k = 0; k < 64; k++) {
        float vk = __shfl(x, k);
        a0 = fmaf(vk, cw1[k * CHH + lane], a0);
        a1 = fmaf(vk, cw1[k * CHH + lane + 64], a1);
    }
    a0 = fmaxf(a0, 0.f); a1 = fmaxf(a1, 0.f);
    float p0 = a0 * cw2[lane * 2] + a1 * cw2[(lane + 64) * 2];
    float p1 = a0 * cw2[lane * 2 + 1] + a1 * cw2[(lane + 64) * 2 + 1];
    for (int off = 32; off; off >>= 1) { p0 += __shfl_xor(p0, off); p1 += __shfl_xor(p1, off); }
    if (lane == 0) {
        float mx = fmaxf(p0, p1);
        float q0 = __expf(p0 - mx), q1 = __expf(p1 - mx);
        float d = q0 + q1;
        outp[b * 2] = q0 / d;
        outp[b * 2 + 1] = q1 / d;
    }
}

extern "C" void kernel_launch(void* const* d_in, const int* in_sizes, int n_in,
                              void* d_out, int out_size, void* d_ws, size_t ws_size,
                              hipStream_t stream)
{
    const float* feats0 = (const float*)d_in[0];
    const float* feats1 = (const float*)d_in[1];
    const float* t0_pw = (const float*)d_in[2];
    const float* t0_pb = (const float*)d_in[3];
    const float* t0_w2 = (const float*)d_in[4];
    const float* t0_b2 = (const float*)d_in[5];
    const float* t0_g  = (const float*)d_in[6];
    const float* t0_be = (const float*)d_in[7];
    const float* t1_pw = (const float*)d_in[8];
    const float* t1_pb = (const float*)d_in[9];
    const float* t1_w2 = (const float*)d_in[10];
    const float* t1_b2 = (const float*)d_in[11];
    const float* t1_g  = (const float*)d_in[12];
    const float* t1_be = (const float*)d_in[13];
    const float* r_vec = (const float*)d_in[14];
    const float* attn_user = (const float*)d_in[15];
    const float* attn_item = (const float*)d_in[16];
    const float* su_w1 = (const float*)d_in[17];
    const float* su_b1 = (const float*)d_in[18];
    const float* su_w2 = (const float*)d_in[19];
    const float* si_w1 = (const float*)d_in[20];
    const float* si_b1 = (const float*)d_in[21];
    const float* si_w2 = (const float*)d_in[22];
    const float* cw1 = (const float*)d_in[23];
    const float* cb1 = (const float*)d_in[24];
    const float* cw2 = (const float*)d_in[25];
    const int* idx0 = (const int*)d_in[26];
    const int* idx1 = (const int*)d_in[27];
    const int* emi_user = (const int*)d_in[28];
    const int* tgt_user = (const int*)d_in[29];
    const int* emi_item = (const int*)d_in[30];
    const int* tgt_item = (const int*)d_in[31];
    float* outp = (float*)d_out;

    // workspace layout
    char* ws = (char*)d_ws;
    float* feat    = (float*)(ws + 0);              // 10,240,000
    float2* rot2   = (float2*)(ws + 10240000);      // 512
    float* s_acc   = (float*)(ws + 10240512);       // 16 (pad 256)
    int*   cnt     = (int*)(ws + 10240768);         // 131072
    int*   cur     = (int*)(ws + 10371840);         // 131072
    int*   offs    = (int*)(ws + 10502912);         // 131088 (pad)
    int*   perm    = (int*)(ws + 10634240);         // 3,200,000
    float* beta    = (float*)(ws + 13834240);       // 16 (pad 256)
    float* ret_buf = (float*)(ws + 13834496);       // 8,388,608
    // total ~22.2 MB

    tower_kernel<<<(NN0 + 63) / 64, 256, 0, stream>>>(feats0, t0_pw, t0_pb, t0_w2, t0_b2,
                                                      t0_g, t0_be, idx0, feat, NN0);
    tower_kernel<<<(NN1 + 63) / 64, 256, 0, stream>>>(feats1, t1_pw, t1_pb, t1_w2, t1_b2,
                                                      t1_g, t1_be, idx1, feat, NN1);
    rot_kernel<<<1, 32, 0, stream>>>(r_vec, rot2);

    // CSR build (cnt + cur contiguous -> one memset; s_acc zero in same region? separate small one)
    hipMemsetAsync(cnt, 0, 2 * 4 * BBB * sizeof(int), stream);
    hipMemsetAsync(s_acc, 0, 4 * sizeof(float), stream);
    hist_kernel<<<dim3((EEE + 255) / 256, 4), 256, 0, stream>>>(tgt_user, tgt_item, cnt);
    scan_kernel<<<4, 256, 0, stream>>>(cnt, offs);
    scatter_kernel<<<dim3((EEE + 255) / 256, 4), 256, 0, stream>>>(tgt_user, tgt_item, offs, cur, perm);

    // fused metapath aggregation + semantic scores
    flash_mp<<<dim3(BBB / 4, 4), 256, 0, stream>>>(feat, emi_user, emi_item, offs, perm,
                                                   attn_user, attn_item, rot2,
                                                   su_w1, su_b1, su_w2, si_w1, si_b1, si_w2,
                                                   s_acc, ret_buf);

    beta_kernel<<<1, 64, 0, stream>>>(s_acc, beta);
    final_kernel<<<BBB / 4, 256, 0, stream>>>(ret_buf, beta, cw1, cb1, cw2, outp);
}

// Round 4
// 442.197 us; speedup vs baseline: 3.0080x; 1.2338x over previous
//
#include <hip/hip_runtime.h>
#include <math.h>

// MAGNN link prediction forward — fp32 throughout.
#define NN0 20000
#define NN1 20000
#define NTOT 40000
#define FF0 512
#define HIDD 64
#define EEE 200000
#define BBB 8192
#define AVV 128
#define CHH 128

__device__ __forceinline__ float fast_tanh(float x) {
    float e2 = __expf(2.f * x);
    return 1.f - 2.f / (e2 + 1.f);
}

// ---------------- tower: Linear(512->64) + GELU + Linear(64->64) + residual + LN ----------------
// grid.y selects tower 0/1 so both run in one launch (626 blocks fill the GPU in one round).
__global__ __launch_bounds__(256) void tower_kernel(
    const float* __restrict__ x0, const float* __restrict__ x1,
    const float* __restrict__ pw0, const float* __restrict__ pw1,
    const float* __restrict__ pb0, const float* __restrict__ pb1,
    const float* __restrict__ w20, const float* __restrict__ w21,
    const float* __restrict__ b20, const float* __restrict__ b21,
    const float* __restrict__ g0, const float* __restrict__ g1,
    const float* __restrict__ be0, const float* __restrict__ be1,
    const int* __restrict__ idxa, const int* __restrict__ idxb,
    float* __restrict__ feat)
{
    int tw = blockIdx.y;
    const float* x  = tw ? x1 : x0;
    const float* pw = tw ? pw1 : pw0;
    const float* pb = tw ? pb1 : pb0;
    const float* w2 = tw ? w21 : w20;
    const float* b2 = tw ? b21 : b20;
    const float* g  = tw ? g1 : g0;
    const float* be = tw ? be1 : be0;
    const int* idx  = tw ? idxb : idxa;
    int nrows = NN0;

    __shared__ float xs[64][68];
    __shared__ float wsh[64][64];
    __shared__ float hs[64][68];
    int tid = threadIdx.x;
    int ct = tid & 15, rt = tid >> 4;
    int row0 = blockIdx.x * 64;

    float acc[4][4];
#pragma unroll
    for (int j = 0; j < 4; j++)
#pragma unroll
        for (int i = 0; i < 4; i++) acc[j][i] = 0.f;

    for (int k0 = 0; k0 < FF0; k0 += 64) {
        for (int li = tid; li < 1024; li += 256) {
            int r = li >> 4, k4 = (li & 15) * 4;
            float4 v = make_float4(0.f, 0.f, 0.f, 0.f);
            int gr = row0 + r;
            if (gr < nrows) v = *(const float4*)&x[(long)gr * FF0 + k0 + k4];
            *(float4*)&xs[r][k4] = v;
        }
        const float4* pw4 = (const float4*)(pw + k0 * 64);
        for (int li = tid; li < 1024; li += 256) {
            float4 v = pw4[li];
            *(float4*)&wsh[li >> 4][(li & 15) * 4] = v;
        }
        __syncthreads();
        for (int k = 0; k < 64; k += 4) {
            float4 xv[4];
#pragma unroll
            for (int j = 0; j < 4; j++) xv[j] = *(const float4*)&xs[4 * rt + j][k];
#pragma unroll
            for (int kk = 0; kk < 4; kk++) {
                float4 wv = *(const float4*)&wsh[k + kk][4 * ct];
#pragma unroll
                for (int j = 0; j < 4; j++) {
                    float xx = kk == 0 ? xv[j].x : kk == 1 ? xv[j].y : kk == 2 ? xv[j].z : xv[j].w;
                    acc[j][0] = fmaf(xx, wv.x, acc[j][0]);
                    acc[j][1] = fmaf(xx, wv.y, acc[j][1]);
                    acc[j][2] = fmaf(xx, wv.z, acc[j][2]);
                    acc[j][3] = fmaf(xx, wv.w, acc[j][3]);
                }
            }
        }
        __syncthreads();
    }

    float4 pbv = *(const float4*)&pb[4 * ct];
    float z[4][4];
#pragma unroll
    for (int j = 0; j < 4; j++) {
        z[j][0] = acc[j][0] + pbv.x; z[j][1] = acc[j][1] + pbv.y;
        z[j][2] = acc[j][2] + pbv.z; z[j][3] = acc[j][3] + pbv.w;
        float4 hv;
        hv.x = 0.5f * z[j][0] * (1.f + erff(z[j][0] * 0.70710678118654752f));
        hv.y = 0.5f * z[j][1] * (1.f + erff(z[j][1] * 0.70710678118654752f));
        hv.z = 0.5f * z[j][2] * (1.f + erff(z[j][2] * 0.70710678118654752f));
        hv.w = 0.5f * z[j][3] * (1.f + erff(z[j][3] * 0.70710678118654752f));
        *(float4*)&hs[4 * rt + j][4 * ct] = hv;
    }
    const float4* w24 = (const float4*)w2;
    for (int li = tid; li < 1024; li += 256) {
        float4 v = w24[li];
        *(float4*)&wsh[li >> 4][(li & 15) * 4] = v;
    }
    __syncthreads();

    float4 b2v = *(const float4*)&b2[4 * ct];
    float acc2[4][4];
#pragma unroll
    for (int j = 0; j < 4; j++) {
        acc2[j][0] = z[j][0] + b2v.x; acc2[j][1] = z[j][1] + b2v.y;
        acc2[j][2] = z[j][2] + b2v.z; acc2[j][3] = z[j][3] + b2v.w;
    }
    for (int k = 0; k < 64; k += 4) {
        float4 xv[4];
#pragma unroll
        for (int j = 0; j < 4; j++) xv[j] = *(const float4*)&hs[4 * rt + j][k];
#pragma unroll
        for (int kk = 0; kk < 4; kk++) {
            float4 wv = *(const float4*)&wsh[k + kk][4 * ct];
#pragma unroll
            for (int j = 0; j < 4; j++) {
                float xx = kk == 0 ? xv[j].x : kk == 1 ? xv[j].y : kk == 2 ? xv[j].z : xv[j].w;
                acc2[j][0] = fmaf(xx, wv.x, acc2[j][0]);
                acc2[j][1] = fmaf(xx, wv.y, acc2[j][1]);
                acc2[j][2] = fmaf(xx, wv.z, acc2[j][2]);
                acc2[j][3] = fmaf(xx, wv.w, acc2[j][3]);
            }
        }
    }
    __syncthreads();
#pragma unroll
    for (int j = 0; j < 4; j++)
        *(float4*)&xs[4 * rt + j][4 * ct] = make_float4(acc2[j][0], acc2[j][1], acc2[j][2], acc2[j][3]);
    __syncthreads();

    int lane = tid & 63, wid = tid >> 6;
    float gc = g[lane], bec = be[lane];
    for (int rr = wid; rr < 64; rr += 4) {
        float y = xs[rr][lane];
        float mu = y;
        for (int off = 32; off; off >>= 1) mu += __shfl_xor(mu, off);
        mu *= (1.f / 64.f);
        float d = y - mu;
        float var = d * d;
        for (int off = 32; off; off >>= 1) var += __shfl_xor(var, off);
        var *= (1.f / 64.f);
        float o = d / sqrtf(var + 1e-5f) * gc + bec;
        int grow = row0 + rr;
        if (grow < nrows) feat[(long)idx[grow] * HIDD + lane] = o;
    }
}

// ---------------- CSR build ----------------
__global__ void hist_kernel(const int* __restrict__ tgt_user, const int* __restrict__ tgt_item,
                            int* __restrict__ cnt)
{
    int combo = blockIdx.y;
    const int* tgt = (combo < 2 ? tgt_user : tgt_item) + (long)(combo & 1) * EEE;
    int i = blockIdx.x * 256 + threadIdx.x;
    if (i < EEE) atomicAdd(&cnt[combo * BBB + tgt[i]], 1);
}

__global__ __launch_bounds__(256) void scan_kernel(const int* __restrict__ cnt, int* __restrict__ offs,
                                                   float* __restrict__ s_acc)
{
    int pth = blockIdx.x;
    if (pth == 0 && threadIdx.x < 4) s_acc[threadIdx.x] = 0.f;
    const int* c = cnt + pth * BBB;
    int* o = offs + pth * (BBB + 1);
    __shared__ int part[256];
    int tid = threadIdx.x;
    int base = tid * 32;
    int local[32];
    int sum = 0;
    for (int j = 0; j < 32; j++) { local[j] = sum; sum += c[base + j]; }
    part[tid] = sum;
    __syncthreads();
    for (int d = 1; d < 256; d <<= 1) {
        int v = (tid >= d) ? part[tid - d] : 0;
        __syncthreads();
        part[tid] += v;
        __syncthreads();
    }
    int pre = (tid == 0) ? 0 : part[tid - 1];
    for (int j = 0; j < 32; j++) o[base + j] = pre + local[j];
    if (tid == 255) o[BBB] = pre + sum;
}

// scatter node TRIPLES in CSR order (kills the perm->emi indirection in flash_mp)
__global__ void scatter_kernel(const int* __restrict__ tgt_user, const int* __restrict__ tgt_item,
                               const int* __restrict__ emi_user, const int* __restrict__ emi_item,
                               const int* __restrict__ offs, int* __restrict__ cur,
                               int4* __restrict__ nodes4)
{
    int combo = blockIdx.y;
    const int* tgt = (combo < 2 ? tgt_user : tgt_item) + (long)(combo & 1) * EEE;
    const int* emi = (combo < 2 ? emi_user : emi_item) + (long)(combo & 1) * EEE * 3;
    int i = blockIdx.x * 256 + threadIdx.x;
    if (i < EEE) {
        int t = tgt[i];
        int pos = offs[combo * (BBB + 1) + t] + atomicAdd(&cur[combo * BBB + t], 1);
        nodes4[(long)combo * EEE + pos] = make_int4(emi[3 * i], emi[3 * i + 1], emi[3 * i + 2], 0);
    }
}

// ---------------- flash metapath + fused semantic-score epilogue ----------------
// one 64-lane wave per (target, combo); lane owns a complex pair; each 32-lane half
// processes 2 instances per iteration (4/iter total); 2-stage software pipeline.
__global__ __launch_bounds__(256) void flash_mp(
    const float* __restrict__ feat, const int4* __restrict__ nodes4,
    const int* __restrict__ offs, const float* __restrict__ r_vec,
    const float* __restrict__ attn_user, const float* __restrict__ attn_item,
    const float* __restrict__ su_w1, const float* __restrict__ su_b1, const float* __restrict__ su_w2,
    const float* __restrict__ si_w1, const float* __restrict__ si_b1, const float* __restrict__ si_w2,
    float* __restrict__ s_acc, float* __restrict__ ret)
{
    int combo = blockIdx.y;
    int wid = threadIdx.x >> 6, lane = threadIdx.x & 63;
    int half = lane >> 5, p = lane & 31;
    int side = combo >> 1;
    const float* attn = (side == 0 ? attn_user : attn_item) + (combo & 1) * 64;
    const float2* f2 = (const float2*)feat;
    // middle-node rotation: normalize r_vec etype-0 row; user side takes conj
    float2 rb = ((const float2*)r_vec)[p];
    float invn = 1.f / sqrtf(rb.x * rb.x + rb.y * rb.y);
    float rvx = rb.x * invn, rvy = rb.y * invn;
    if (side == 0) rvy = -rvy;
    float aRe = attn[2 * p], aIm = attn[2 * p + 1];
    int t = blockIdx.x * 4 + wid;
    int beg = offs[combo * (BBB + 1) + t], end = offs[combo * (BBB + 1) + t + 1];
    int n = end - beg;
    const int4* nd = nodes4 + (long)combo * EEE;

    float m = -3.4e38f, s = 0.f, Ox = 0.f, Oy = 0.f;

    float2 cA0, cA1, cA2, cB0, cB1, cB2;
    int4 nA, nB;
    if (n > 0) {
        int ia = beg + half;            if (ia >= end) ia = end - 1;
        int ib = beg + 2 + half;        if (ib >= end) ib = end - 1;
        int4 a = nd[ia], b = nd[ib];
        cA0 = f2[a.x * 32 + p]; cA1 = f2[a.y * 32 + p]; cA2 = f2[a.z * 32 + p];
        cB0 = f2[b.x * 32 + p]; cB1 = f2[b.y * 32 + p]; cB2 = f2[b.z * 32 + p];
        int ja = beg + 4 + half;        if (ja >= end) ja = end - 1;
        int jb = beg + 6 + half;        if (jb >= end) jb = end - 1;
        nA = nd[ja]; nB = nd[jb];
    }
    for (int it = 0; it < n; it += 4) {
        float2 uA0 = cA0, uA1 = cA1, uA2 = cA2, uB0 = cB0, uB1 = cB1, uB2 = cB2;
        if (it + 4 < n) {
            cA0 = f2[nA.x * 32 + p]; cA1 = f2[nA.y * 32 + p]; cA2 = f2[nA.z * 32 + p];
            cB0 = f2[nB.x * 32 + p]; cB1 = f2[nB.y * 32 + p]; cB2 = f2[nB.z * 32 + p];
            int ja = beg + it + 8 + half;   if (ja >= end) ja = end - 1;
            int jb = beg + it + 10 + half;  if (jb >= end) jb = end - 1;
            nA = nd[ja]; nB = nd[jb];
        }
        float reA = (uA0.x + uA2.x + uA1.x * rvx - uA1.y * rvy) * (1.f / 3.f);
        float imA = (uA0.y + uA2.y + uA1.x * rvy + uA1.y * rvx) * (1.f / 3.f);
        float reB = (uB0.x + uB2.x + uB1.x * rvx - uB1.y * rvy) * (1.f / 3.f);
        float imB = (uB0.y + uB2.y + uB1.x * rvy + uB1.y * rvx) * (1.f / 3.f);
        float pa = reA * aRe + imA * aIm;
        float pb = reB * aRe + imB * aIm;
        pa += __shfl_xor(pa, 1); pa += __shfl_xor(pa, 2);
        pb += __shfl_xor(pb, 1); pb += __shfl_xor(pb, 2);
        float eA = pa > 0.f ? pa : 0.01f * pa;   // leaky_relu
        float eB = pb > 0.f ? pb : 0.01f * pb;
        if (it + half >= n) eA = -3.4e38f;
        if (it + 2 + half >= n) eB = -3.4e38f;
        float eAo = __shfl_xor(eA, 32), eBo = __shfl_xor(eB, 32);
        float mn = fmaxf(m, fmaxf(fmaxf(eA, eB), fmaxf(eAo, eBo)));
        float alpha = __expf(m - mn);
        float wA = __expf(eA - mn), wB = __expf(eB - mn);
        float wl = wA + wB;
        float wsum = wl + __shfl_xor(wl, 32);
        s = s * alpha + wsum;
        Ox = Ox * alpha + wA * reA + wB * reB;
        Oy = Oy * alpha + wA * imA + wB * imB;
        m = mn;
    }
    // combine halves (state s,m replicated; O split by half)
    float sx = __shfl_xor(Ox, 32), sy = __shfl_xor(Oy, 32);
    float inv = 1.f / (s + 1e-9f);
    float vx = (Ox + sx) * inv, vy = (Oy + sy) * inv;
    vx = vx > 0.f ? vx : __expf(vx) - 1.f;   // ELU
    vy = vy > 0.f ? vy : __expf(vy) - 1.f;
    if (half == 0)
        ((float2*)ret)[((long)combo * BBB + t) * 32 + p] = make_float2(vx, vy);

    // fused semantic score: tanh(v @ w1 + b1) @ w2, summed over rows
    const float* w1 = side == 0 ? su_w1 : si_w1;
    const float* b1 = side == 0 ? su_b1 : si_b1;
    const float* w2 = side == 0 ? su_w2 : si_w2;
    float a0 = b1[lane], a1 = b1[lane + 64];
    for (int k = 0; k < 64; k++) {
        float vk = __shfl((k & 1) ? vy : vx, k >> 1);
        a0 = fmaf(vk, w1[k * AVV + lane], a0);
        a1 = fmaf(vk, w1[k * AVV + lane + 64], a1);
    }
    float total = fast_tanh(a0) * w2[lane] + fast_tanh(a1) * w2[lane + 64];
    for (int off = 32; off; off >>= 1) total += __shfl_xor(total, off);
    __shared__ float red[4];
    if (lane == 0) red[wid] = total;
    __syncthreads();
    if (threadIdx.x == 0) atomicAdd(&s_acc[combo], red[0] + red[1] + red[2] + red[3]);
}

// ---------------- final product MLP + softmax (beta computed inline) ----------------
__global__ __launch_bounds__(256) void final_kernel(
    const float* __restrict__ ret, const float* __restrict__ s_acc,
    const float* __restrict__ cw1, const float* __restrict__ cb1, const float* __restrict__ cw2,
    float* __restrict__ outp)
{
    float s0 = s_acc[0] * (1.f / BBB), s1 = s_acc[1] * (1.f / BBB);
    float s2 = s_acc[2] * (1.f / BBB), s3 = s_acc[3] * (1.f / BBB);
    float mu = fmaxf(s0, s1);
    float e0 = __expf(s0 - mu), e1 = __expf(s1 - mu);
    float bu0 = e0 / (e0 + e1), bu1 = e1 / (e0 + e1);
    float mi = fmaxf(s2, s3);
    float f0 = __expf(s2 - mi), f1 = __expf(s3 - mi);
    float bi0 = f0 / (f0 + f1), bi1 = f1 / (f0 + f1);

    int wid = threadIdx.x >> 6, lane = threadIdx.x & 63;
    int b = blockIdx.x * 4 + wid;
    if (b >= BBB) return;
    float hu = bu0 * ret[(long)0 * BBB * HIDD + (long)b * HIDD + lane]
             + bu1 * ret[(long)1 * BBB * HIDD + (long)b * HIDD + lane];
    float hi = bi0 * ret[(long)2 * BBB * HIDD + (long)b * HIDD + lane]
             + bi1 * ret[(long)3 * BBB * HIDD + (long)b * HIDD + lane];
    float x = hu * hi;
    float a0 = cb1[lane], a1 = cb1[lane + 64];
    for (int k = 0; k < 64; k++) {
        float vk = __shfl(x, k);
        a0 = fmaf(vk, cw1[k * CHH + lane], a0);
        a1 = fmaf(vk, cw1[k * CHH + lane + 64], a1);
    }
    a0 = fmaxf(a0, 0.f); a1 = fmaxf(a1, 0.f);
    float p0 = a0 * cw2[lane * 2] + a1 * cw2[(lane + 64) * 2];
    float p1 = a0 * cw2[lane * 2 + 1] + a1 * cw2[(lane + 64) * 2 + 1];
    for (int off = 32; off; off >>= 1) { p0 += __shfl_xor(p0, off); p1 += __shfl_xor(p1, off); }
    if (lane == 0) {
        float mx = fmaxf(p0, p1);
        float q0 = __expf(p0 - mx), q1 = __expf(p1 - mx);
        float d = q0 + q1;
        outp[b * 2] = q0 / d;
        outp[b * 2 + 1] = q1 / d;
    }
}

extern "C" void kernel_launch(void* const* d_in, const int* in_sizes, int n_in,
                              void* d_out, int out_size, void* d_ws, size_t ws_size,
                              hipStream_t stream)
{
    const float* feats0 = (const float*)d_in[0];
    const float* feats1 = (const float*)d_in[1];
    const float* t0_pw = (const float*)d_in[2];
    const float* t0_pb = (const float*)d_in[3];
    const float* t0_w2 = (const float*)d_in[4];
    const float* t0_b2 = (const float*)d_in[5];
    const float* t0_g  = (const float*)d_in[6];
    const float* t0_be = (const float*)d_in[7];
    const float* t1_pw = (const float*)d_in[8];
    const float* t1_pb = (const float*)d_in[9];
    const float* t1_w2 = (const float*)d_in[10];
    const float* t1_b2 = (const float*)d_in[11];
    const float* t1_g  = (const float*)d_in[12];
    const float* t1_be = (const float*)d_in[13];
    const float* r_vec = (const float*)d_in[14];
    const float* attn_user = (const float*)d_in[15];
    const float* attn_item = (const float*)d_in[16];
    const float* su_w1 = (const float*)d_in[17];
    const float* su_b1 = (const float*)d_in[18];
    const float* su_w2 = (const float*)d_in[19];
    const float* si_w1 = (const float*)d_in[20];
    const float* si_b1 = (const float*)d_in[21];
    const float* si_w2 = (const float*)d_in[22];
    const float* cw1 = (const float*)d_in[23];
    const float* cb1 = (const float*)d_in[24];
    const float* cw2 = (const float*)d_in[25];
    const int* idx0 = (const int*)d_in[26];
    const int* idx1 = (const int*)d_in[27];
    const int* emi_user = (const int*)d_in[28];
    const int* tgt_user = (const int*)d_in[29];
    const int* emi_item = (const int*)d_in[30];
    const int* tgt_item = (const int*)d_in[31];
    float* outp = (float*)d_out;

    // workspace layout (256B aligned)
    char* ws = (char*)d_ws;
    float* feat   = (float*)(ws + 0);               // 10,240,000
    int*   cnt    = (int*)(ws + 10240000);          // 131,072
    int*   cur    = (int*)(ws + 10371072);          // 131,072
    int*   offs   = (int*)(ws + 10502144);          // 131,088 (pad to 131,328)
    int4*  nodes4 = (int4*)(ws + 10633472);         // 4*200000*16 = 12,800,000
    float* s_acc  = (float*)(ws + 23433472);        // 256
    float* ret_buf= (float*)(ws + 23433728);        // 8,388,608  (end ~31.8 MB)

    tower_kernel<<<dim3((NN0 + 63) / 64, 2), 256, 0, stream>>>(
        feats0, feats1, t0_pw, t1_pw, t0_pb, t1_pb, t0_w2, t1_w2,
        t0_b2, t1_b2, t0_g, t1_g, t0_be, t1_be, idx0, idx1, feat);

    hipMemsetAsync(cnt, 0, 2 * 4 * BBB * sizeof(int), stream);
    hist_kernel<<<dim3((EEE + 255) / 256, 4), 256, 0, stream>>>(tgt_user, tgt_item, cnt);
    scan_kernel<<<4, 256, 0, stream>>>(cnt, offs, s_acc);
    scatter_kernel<<<dim3((EEE + 255) / 256, 4), 256, 0, stream>>>(
        tgt_user, tgt_item, emi_user, emi_item, offs, cur, nodes4);

    flash_mp<<<dim3(BBB / 4, 4), 256, 0, stream>>>(feat, nodes4, offs, r_vec,
                                                   attn_user, attn_item,
                                                   su_w1, su_b1, su_w2, si_w1, si_b1, si_w2,
                                                   s_acc, ret_buf);

    final_kernel<<<BBB / 4, 256, 0, stream>>>(ret_buf, s_acc, cw1, cb1, cw2, outp);
}

// Round 5
// 430.964 us; speedup vs baseline: 3.0864x; 1.0261x over previous
//
#include <hip/hip_runtime.h>
#include <hip/hip_bf16.h>
#include <math.h>

// MAGNN link prediction forward — fp32 compute; feat table stored bf16 for gather BW.
#define NN0 20000
#define NN1 20000
#define NTOT 40000
#define FF0 512
#define HIDD 64
#define EEE 200000
#define BBB 8192
#define AVV 128
#define CHH 128

__device__ __forceinline__ float fast_tanh(float x) {
    float e2 = __expf(2.f * x);
    return 1.f - 2.f / (e2 + 1.f);
}

// ---------------- tower: Linear(512->64) + GELU + Linear(64->64) + residual + LN ----------------
__global__ __launch_bounds__(256) void tower_kernel(
    const float* __restrict__ x0, const float* __restrict__ x1,
    const float* __restrict__ pw0, const float* __restrict__ pw1,
    const float* __restrict__ pb0, const float* __restrict__ pb1,
    const float* __restrict__ w20, const float* __restrict__ w21,
    const float* __restrict__ b20, const float* __restrict__ b21,
    const float* __restrict__ g0, const float* __restrict__ g1,
    const float* __restrict__ be0, const float* __restrict__ be1,
    const int* __restrict__ idxa, const int* __restrict__ idxb,
    __hip_bfloat16* __restrict__ feat)
{
    int tw = blockIdx.y;
    const float* x  = tw ? x1 : x0;
    const float* pw = tw ? pw1 : pw0;
    const float* pb = tw ? pb1 : pb0;
    const float* w2 = tw ? w21 : w20;
    const float* b2 = tw ? b21 : b20;
    const float* g  = tw ? g1 : g0;
    const float* be = tw ? be1 : be0;
    const int* idx  = tw ? idxb : idxa;
    int nrows = NN0;

    __shared__ float xs[64][68];
    __shared__ float wsh[64][64];
    __shared__ float hs[64][68];
    int tid = threadIdx.x;
    int ct = tid & 15, rt = tid >> 4;
    int row0 = blockIdx.x * 64;

    float acc[4][4];
#pragma unroll
    for (int j = 0; j < 4; j++)
#pragma unroll
        for (int i = 0; i < 4; i++) acc[j][i] = 0.f;

    for (int k0 = 0; k0 < FF0; k0 += 64) {
        for (int li = tid; li < 1024; li += 256) {
            int r = li >> 4, k4 = (li & 15) * 4;
            float4 v = make_float4(0.f, 0.f, 0.f, 0.f);
            int gr = row0 + r;
            if (gr < nrows) v = *(const float4*)&x[(long)gr * FF0 + k0 + k4];
            *(float4*)&xs[r][k4] = v;
        }
        const float4* pw4 = (const float4*)(pw + k0 * 64);
        for (int li = tid; li < 1024; li += 256) {
            float4 v = pw4[li];
            *(float4*)&wsh[li >> 4][(li & 15) * 4] = v;
        }
        __syncthreads();
        for (int k = 0; k < 64; k += 4) {
            float4 xv[4];
#pragma unroll
            for (int j = 0; j < 4; j++) xv[j] = *(const float4*)&xs[4 * rt + j][k];
#pragma unroll
            for (int kk = 0; kk < 4; kk++) {
                float4 wv = *(const float4*)&wsh[k + kk][4 * ct];
#pragma unroll
                for (int j = 0; j < 4; j++) {
                    float xx = kk == 0 ? xv[j].x : kk == 1 ? xv[j].y : kk == 2 ? xv[j].z : xv[j].w;
                    acc[j][0] = fmaf(xx, wv.x, acc[j][0]);
                    acc[j][1] = fmaf(xx, wv.y, acc[j][1]);
                    acc[j][2] = fmaf(xx, wv.z, acc[j][2]);
                    acc[j][3] = fmaf(xx, wv.w, acc[j][3]);
                }
            }
        }
        __syncthreads();
    }

    float4 pbv = *(const float4*)&pb[4 * ct];
    float z[4][4];
#pragma unroll
    for (int j = 0; j < 4; j++) {
        z[j][0] = acc[j][0] + pbv.x; z[j][1] = acc[j][1] + pbv.y;
        z[j][2] = acc[j][2] + pbv.z; z[j][3] = acc[j][3] + pbv.w;
        float4 hv;
        hv.x = 0.5f * z[j][0] * (1.f + erff(z[j][0] * 0.70710678118654752f));
        hv.y = 0.5f * z[j][1] * (1.f + erff(z[j][1] * 0.70710678118654752f));
        hv.z = 0.5f * z[j][2] * (1.f + erff(z[j][2] * 0.70710678118654752f));
        hv.w = 0.5f * z[j][3] * (1.f + erff(z[j][3] * 0.70710678118654752f));
        *(float4*)&hs[4 * rt + j][4 * ct] = hv;
    }
    const float4* w24 = (const float4*)w2;
    for (int li = tid; li < 1024; li += 256) {
        float4 v = w24[li];
        *(float4*)&wsh[li >> 4][(li & 15) * 4] = v;
    }
    __syncthreads();

    float4 b2v = *(const float4*)&b2[4 * ct];
    float acc2[4][4];
#pragma unroll
    for (int j = 0; j < 4; j++) {
        acc2[j][0] = z[j][0] + b2v.x; acc2[j][1] = z[j][1] + b2v.y;
        acc2[j][2] = z[j][2] + b2v.z; acc2[j][3] = z[j][3] + b2v.w;
    }
    for (int k = 0; k < 64; k += 4) {
        float4 xv[4];
#pragma unroll
        for (int j = 0; j < 4; j++) xv[j] = *(const float4*)&hs[4 * rt + j][k];
#pragma unroll
        for (int kk = 0; kk < 4; kk++) {
            float4 wv = *(const float4*)&wsh[k + kk][4 * ct];
#pragma unroll
            for (int j = 0; j < 4; j++) {
                float xx = kk == 0 ? xv[j].x : kk == 1 ? xv[j].y : kk == 2 ? xv[j].z : xv[j].w;
                acc2[j][0] = fmaf(xx, wv.x, acc2[j][0]);
                acc2[j][1] = fmaf(xx, wv.y, acc2[j][1]);
                acc2[j][2] = fmaf(xx, wv.z, acc2[j][2]);
                acc2[j][3] = fmaf(xx, wv.w, acc2[j][3]);
            }
        }
    }
    __syncthreads();
#pragma unroll
    for (int j = 0; j < 4; j++)
        *(float4*)&xs[4 * rt + j][4 * ct] = make_float4(acc2[j][0], acc2[j][1], acc2[j][2], acc2[j][3]);
    __syncthreads();

    int lane = tid & 63, wid = tid >> 6;
    float gc = g[lane], bec = be[lane];
    for (int rr = wid; rr < 64; rr += 4) {
        float y = xs[rr][lane];
        float mu = y;
        for (int off = 32; off; off >>= 1) mu += __shfl_xor(mu, off);
        mu *= (1.f / 64.f);
        float d = y - mu;
        float var = d * d;
        for (int off = 32; off; off >>= 1) var += __shfl_xor(var, off);
        var *= (1.f / 64.f);
        float o = d / sqrtf(var + 1e-5f) * gc + bec;
        int grow = row0 + rr;
        if (grow < nrows) feat[(long)idx[grow] * HIDD + lane] = __float2bfloat16(o);
    }
}

// ---------------- CSR build ----------------
__global__ void hist_kernel(const int* __restrict__ tgt_user, const int* __restrict__ tgt_item,
                            int* __restrict__ cnt)
{
    int combo = blockIdx.y;
    const int* tgt = (combo < 2 ? tgt_user : tgt_item) + (long)(combo & 1) * EEE;
    int i = blockIdx.x * 256 + threadIdx.x;
    if (i < EEE) atomicAdd(&cnt[combo * BBB + tgt[i]], 1);
}

__global__ __launch_bounds__(256) void scan_kernel(const int* __restrict__ cnt, int* __restrict__ offs,
                                                   float* __restrict__ s_acc)
{
    int pth = blockIdx.x;
    if (pth == 0 && threadIdx.x < 4) s_acc[threadIdx.x] = 0.f;
    const int* c = cnt + pth * BBB;
    int* o = offs + pth * (BBB + 1);
    __shared__ int part[256];
    int tid = threadIdx.x;
    int base = tid * 32;
    int local[32];
    int sum = 0;
    for (int j = 0; j < 32; j++) { local[j] = sum; sum += c[base + j]; }
    part[tid] = sum;
    __syncthreads();
    for (int d = 1; d < 256; d <<= 1) {
        int v = (tid >= d) ? part[tid - d] : 0;
        __syncthreads();
        part[tid] += v;
        __syncthreads();
    }
    int pre = (tid == 0) ? 0 : part[tid - 1];
    for (int j = 0; j < 32; j++) o[base + j] = pre + local[j];
    if (tid == 255) o[BBB] = pre + sum;
}

// scatter node TRIPLES in CSR order
__global__ void scatter_kernel(const int* __restrict__ tgt_user, const int* __restrict__ tgt_item,
                               const int* __restrict__ emi_user, const int* __restrict__ emi_item,
                               const int* __restrict__ offs, int* __restrict__ cur,
                               int4* __restrict__ nodes4)
{
    int combo = blockIdx.y;
    const int* tgt = (combo < 2 ? tgt_user : tgt_item) + (long)(combo & 1) * EEE;
    const int* emi = (combo < 2 ? emi_user : emi_item) + (long)(combo & 1) * EEE * 3;
    int i = blockIdx.x * 256 + threadIdx.x;
    if (i < EEE) {
        int t = tgt[i];
        int pos = offs[combo * (BBB + 1) + t] + atomicAdd(&cur[combo * BBB + t], 1);
        nodes4[(long)combo * EEE + pos] = make_int4(emi[3 * i], emi[3 * i + 1], emi[3 * i + 2], 0);
    }
}

// ---------------- flash metapath + fused semantic-score epilogue ----------------
// one 64-lane wave per (target, combo); lane owns a complex pair; 4 instance streams
// per half (8 instances/iteration); 2-stage software pipeline; bf16 feat gathers.
__global__ __launch_bounds__(256) void flash_mp(
    const __hip_bfloat16* __restrict__ feat, const int4* __restrict__ nodes4,
    const int* __restrict__ offs, const float* __restrict__ r_vec,
    const float* __restrict__ attn_user, const float* __restrict__ attn_item,
    const float* __restrict__ su_w1, const float* __restrict__ su_b1, const float* __restrict__ su_w2,
    const float* __restrict__ si_w1, const float* __restrict__ si_b1, const float* __restrict__ si_w2,
    float* __restrict__ s_acc, float* __restrict__ ret)
{
    int combo = blockIdx.y;
    int wid = threadIdx.x >> 6, lane = threadIdx.x & 63;
    int half = lane >> 5, p = lane & 31;
    int side = combo >> 1;
    const float* attn = (side == 0 ? attn_user : attn_item) + (combo & 1) * 64;
    const __hip_bfloat162* f2 = (const __hip_bfloat162*)feat;
    float2 rb = ((const float2*)r_vec)[p];
    float invn = 1.f / sqrtf(rb.x * rb.x + rb.y * rb.y);
    float rvx = rb.x * invn, rvy = rb.y * invn;
    if (side == 0) rvy = -rvy;
    float aRe = attn[2 * p], aIm = attn[2 * p + 1];
    int t = blockIdx.x * 4 + wid;
    int beg = offs[combo * (BBB + 1) + t], end = offs[combo * (BBB + 1) + t + 1];
    int n = end - beg;
    const int4* nd = nodes4 + (long)combo * EEE;

    float m = -3.4e38f, s = 0.f, Ox = 0.f, Oy = 0.f;

    __hip_bfloat162 c[4][3];
    int4 nq[4];
    if (n > 0) {
#pragma unroll
        for (int q = 0; q < 4; q++) {
            int j = beg + 2 * q + half; if (j >= end) j = end - 1;
            int4 a = nd[j];
            c[q][0] = f2[a.x * 32 + p];
            c[q][1] = f2[a.y * 32 + p];
            c[q][2] = f2[a.z * 32 + p];
        }
#pragma unroll
        for (int q = 0; q < 4; q++) {
            int j = beg + 8 + 2 * q + half; if (j >= end) j = end - 1;
            nq[q] = nd[j];
        }
    }
    for (int it = 0; it < n; it += 8) {
        // convert current stage to fp32
        float2 u[4][3];
#pragma unroll
        for (int q = 0; q < 4; q++)
#pragma unroll
            for (int r = 0; r < 3; r++)
                u[q][r] = __bfloat1622float2(c[q][r]);
        // advance pipeline
        if (it + 8 < n) {
#pragma unroll
            for (int q = 0; q < 4; q++) {
                c[q][0] = f2[nq[q].x * 32 + p];
                c[q][1] = f2[nq[q].y * 32 + p];
                c[q][2] = f2[nq[q].z * 32 + p];
            }
#pragma unroll
            for (int q = 0; q < 4; q++) {
                int j = beg + it + 16 + 2 * q + half; if (j >= end) j = end - 1;
                nq[q] = nd[j];
            }
        }
        // compute 4 streams
        float re[4], im[4], e[4];
#pragma unroll
        for (int q = 0; q < 4; q++) {
            re[q] = (u[q][0].x + u[q][2].x + u[q][1].x * rvx - u[q][1].y * rvy) * (1.f / 3.f);
            im[q] = (u[q][0].y + u[q][2].y + u[q][1].x * rvy + u[q][1].y * rvx) * (1.f / 3.f);
            float pa = re[q] * aRe + im[q] * aIm;
            pa += __shfl_xor(pa, 1);
            pa += __shfl_xor(pa, 2);
            float ev = pa > 0.f ? pa : 0.01f * pa;      // leaky_relu
            if (it + 2 * q + half >= n) ev = -3.4e38f;
            e[q] = ev;
        }
        float mx = fmaxf(fmaxf(e[0], e[1]), fmaxf(e[2], e[3]));
        float mn = fmaxf(m, fmaxf(mx, __shfl_xor(mx, 32)));
        float alpha = __expf(m - mn);
        float w0 = __expf(e[0] - mn), w1 = __expf(e[1] - mn);
        float w2_ = __expf(e[2] - mn), w3 = __expf(e[3] - mn);
        float wl = (w0 + w1) + (w2_ + w3);
        float wsum = wl + __shfl_xor(wl, 32);
        s = s * alpha + wsum;
        Ox = Ox * alpha + w0 * re[0] + w1 * re[1] + w2_ * re[2] + w3 * re[3];
        Oy = Oy * alpha + w0 * im[0] + w1 * im[1] + w2_ * im[2] + w3 * im[3];
        m = mn;
    }
    float sx = __shfl_xor(Ox, 32), sy = __shfl_xor(Oy, 32);
    float inv = 1.f / (s + 1e-9f);
    float vx = (Ox + sx) * inv, vy = (Oy + sy) * inv;
    vx = vx > 0.f ? vx : __expf(vx) - 1.f;   // ELU
    vy = vy > 0.f ? vy : __expf(vy) - 1.f;
    if (half == 0)
        ((float2*)ret)[((long)combo * BBB + t) * 32 + p] = make_float2(vx, vy);

    // fused semantic score: tanh(v @ w1 + b1) @ w2, summed over rows
    const float* w1p = side == 0 ? su_w1 : si_w1;
    const float* b1p = side == 0 ? su_b1 : si_b1;
    const float* w2p = side == 0 ? su_w2 : si_w2;
    float a0 = b1p[lane], a1 = b1p[lane + 64];
    for (int k = 0; k < 64; k++) {
        float vk = __shfl((k & 1) ? vy : vx, k >> 1);
        a0 = fmaf(vk, w1p[k * AVV + lane], a0);
        a1 = fmaf(vk, w1p[k * AVV + lane + 64], a1);
    }
    float total = fast_tanh(a0) * w2p[lane] + fast_tanh(a1) * w2p[lane + 64];
    for (int off = 32; off; off >>= 1) total += __shfl_xor(total, off);
    __shared__ float red[4];
    if (lane == 0) red[wid] = total;
    __syncthreads();
    if (threadIdx.x == 0) atomicAdd(&s_acc[combo], red[0] + red[1] + red[2] + red[3]);
}

// ---------------- final product MLP + softmax (beta computed inline) ----------------
__global__ __launch_bounds__(256) void final_kernel(
    const float* __restrict__ ret, const float* __restrict__ s_acc,
    const float* __restrict__ cw1, const float* __restrict__ cb1, const float* __restrict__ cw2,
    float* __restrict__ outp)
{
    float s0 = s_acc[0] * (1.f / BBB), s1 = s_acc[1] * (1.f / BBB);
    float s2 = s_acc[2] * (1.f / BBB), s3 = s_acc[3] * (1.f / BBB);
    float mu = fmaxf(s0, s1);
    float e0 = __expf(s0 - mu), e1 = __expf(s1 - mu);
    float bu0 = e0 / (e0 + e1), bu1 = e1 / (e0 + e1);
    float mi = fmaxf(s2, s3);
    float f0 = __expf(s2 - mi), f1 = __expf(s3 - mi);
    float bi0 = f0 / (f0 + f1), bi1 = f1 / (f0 + f1);

    int wid = threadIdx.x >> 6, lane = threadIdx.x & 63;
    int b = blockIdx.x * 4 + wid;
    if (b >= BBB) return;
    float hu = bu0 * ret[(long)0 * BBB * HIDD + (long)b * HIDD + lane]
             + bu1 * ret[(long)1 * BBB * HIDD + (long)b * HIDD + lane];
    float hi = bi0 * ret[(long)2 * BBB * HIDD + (long)b * HIDD + lane]
             + bi1 * ret[(long)3 * BBB * HIDD + (long)b * HIDD + lane];
    float x = hu * hi;
    float a0 = cb1[lane], a1 = cb1[lane + 64];
    for (int k = 0; k < 64; k++) {
        float vk = __shfl(x, k);
        a0 = fmaf(vk, cw1[k * CHH + lane], a0);
        a1 = fmaf(vk, cw1[k * CHH + lane + 64], a1);
    }
    a0 = fmaxf(a0, 0.f); a1 = fmaxf(a1, 0.f);
    float p0 = a0 * cw2[lane * 2] + a1 * cw2[(lane + 64) * 2];
    float p1 = a0 * cw2[lane * 2 + 1] + a1 * cw2[(lane + 64) * 2 + 1];
    for (int off = 32; off; off >>= 1) { p0 += __shfl_xor(p0, off); p1 += __shfl_xor(p1, off); }
    if (lane == 0) {
        float mx = fmaxf(p0, p1);
        float q0 = __expf(p0 - mx), q1 = __expf(p1 - mx);
        float d = q0 + q1;
        outp[b * 2] = q0 / d;
        outp[b * 2 + 1] = q1 / d;
    }
}

extern "C" void kernel_launch(void* const* d_in, const int* in_sizes, int n_in,
                              void* d_out, int out_size, void* d_ws, size_t ws_size,
                              hipStream_t stream)
{
    const float* feats0 = (const float*)d_in[0];
    const float* feats1 = (const float*)d_in[1];
    const float* t0_pw = (const float*)d_in[2];
    const float* t0_pb = (const float*)d_in[3];
    const float* t0_w2 = (const float*)d_in[4];
    const float* t0_b2 = (const float*)d_in[5];
    const float* t0_g  = (const float*)d_in[6];
    const float* t0_be = (const float*)d_in[7];
    const float* t1_pw = (const float*)d_in[8];
    const float* t1_pb = (const float*)d_in[9];
    const float* t1_w2 = (const float*)d_in[10];
    const float* t1_b2 = (const float*)d_in[11];
    const float* t1_g  = (const float*)d_in[12];
    const float* t1_be = (const float*)d_in[13];
    const float* r_vec = (const float*)d_in[14];
    const float* attn_user = (const float*)d_in[15];
    const float* attn_item = (const float*)d_in[16];
    const float* su_w1 = (const float*)d_in[17];
    const float* su_b1 = (const float*)d_in[18];
    const float* su_w2 = (const float*)d_in[19];
    const float* si_w1 = (const float*)d_in[20];
    const float* si_b1 = (const float*)d_in[21];
    const float* si_w2 = (const float*)d_in[22];
    const float* cw1 = (const float*)d_in[23];
    const float* cb1 = (const float*)d_in[24];
    const float* cw2 = (const float*)d_in[25];
    const int* idx0 = (const int*)d_in[26];
    const int* idx1 = (const int*)d_in[27];
    const int* emi_user = (const int*)d_in[28];
    const int* tgt_user = (const int*)d_in[29];
    const int* emi_item = (const int*)d_in[30];
    const int* tgt_item = (const int*)d_in[31];
    float* outp = (float*)d_out;

    // workspace layout (256B aligned)
    char* ws = (char*)d_ws;
    __hip_bfloat16* feat = (__hip_bfloat16*)(ws + 0);   // 40000*64*2 = 5,120,000
    int*   cnt    = (int*)(ws + 5120000);               // 131,072
    int*   cur    = (int*)(ws + 5251072);               // 131,072
    int*   offs   = (int*)(ws + 5382144);               // 131,088 (pad)
    int4*  nodes4 = (int4*)(ws + 5513472);              // 12,800,000
    float* s_acc  = (float*)(ws + 18313472);            // 256
    float* ret_buf= (float*)(ws + 18313728);            // 8,388,608  (end ~26.7 MB)

    tower_kernel<<<dim3((NN0 + 63) / 64, 2), 256, 0, stream>>>(
        feats0, feats1, t0_pw, t1_pw, t0_pb, t1_pb, t0_w2, t1_w2,
        t0_b2, t1_b2, t0_g, t1_g, t0_be, t1_be, idx0, idx1, feat);

    hipMemsetAsync(cnt, 0, 2 * 4 * BBB * sizeof(int), stream);
    hist_kernel<<<dim3((EEE + 255) / 256, 4), 256, 0, stream>>>(tgt_user, tgt_item, cnt);
    scan_kernel<<<4, 256, 0, stream>>>(cnt, offs, s_acc);
    scatter_kernel<<<dim3((EEE + 255) / 256, 4), 256, 0, stream>>>(
        tgt_user, tgt_item, emi_user, emi_item, offs, cur, nodes4);

    flash_mp<<<dim3(BBB / 4, 4), 256, 0, stream>>>(feat, nodes4, offs, r_vec,
                                                   attn_user, attn_item,
                                                   su_w1, su_b1, su_w2, si_w1, si_b1, si_w2,
                                                   s_acc, ret_buf);

    final_kernel<<<BBB / 4, 256, 0, stream>>>(ret_buf, s_acc, cw1, cb1, cw2, outp);
}

// Round 6
// 384.840 us; speedup vs baseline: 3.4563x; 1.1199x over previous
//
#include <hip/hip_runtime.h>
#include <hip/hip_bf16.h>
#include <math.h>

// MAGNN link prediction forward — fp32 compute; feat table stored bf16.
#define NN0 20000
#define NN1 20000
#define NTOT 40000
#define FF0 512
#define HIDD 64
#define EEE 200000
#define BBB 8192
#define AVV 128
#define CHH 128

__device__ __forceinline__ float fast_tanh(float x) {
    float e2 = __expf(2.f * x);
    return 1.f - 2.f / (e2 + 1.f);
}

// ---------------- tower: Linear(512->64) + GELU + Linear(64->64) + residual + LN ----------------
__global__ __launch_bounds__(256) void tower_kernel(
    const float* __restrict__ x0, const float* __restrict__ x1,
    const float* __restrict__ pw0, const float* __restrict__ pw1,
    const float* __restrict__ pb0, const float* __restrict__ pb1,
    const float* __restrict__ w20, const float* __restrict__ w21,
    const float* __restrict__ b20, const float* __restrict__ b21,
    const float* __restrict__ g0, const float* __restrict__ g1,
    const float* __restrict__ be0, const float* __restrict__ be1,
    const int* __restrict__ idxa, const int* __restrict__ idxb,
    __hip_bfloat16* __restrict__ feat)
{
    int tw = blockIdx.y;
    const float* x  = tw ? x1 : x0;
    const float* pw = tw ? pw1 : pw0;
    const float* pb = tw ? pb1 : pb0;
    const float* w2 = tw ? w21 : w20;
    const float* b2 = tw ? b21 : b20;
    const float* g  = tw ? g1 : g0;
    const float* be = tw ? be1 : be0;
    const int* idx  = tw ? idxb : idxa;
    int nrows = NN0;

    __shared__ float xs[64][68];
    __shared__ float wsh[64][64];
    __shared__ float hs[64][68];
    int tid = threadIdx.x;
    int ct = tid & 15, rt = tid >> 4;
    int row0 = blockIdx.x * 64;

    float acc[4][4];
#pragma unroll
    for (int j = 0; j < 4; j++)
#pragma unroll
        for (int i = 0; i < 4; i++) acc[j][i] = 0.f;

    for (int k0 = 0; k0 < FF0; k0 += 64) {
        for (int li = tid; li < 1024; li += 256) {
            int r = li >> 4, k4 = (li & 15) * 4;
            float4 v = make_float4(0.f, 0.f, 0.f, 0.f);
            int gr = row0 + r;
            if (gr < nrows) v = *(const float4*)&x[(long)gr * FF0 + k0 + k4];
            *(float4*)&xs[r][k4] = v;
        }
        const float4* pw4 = (const float4*)(pw + k0 * 64);
        for (int li = tid; li < 1024; li += 256) {
            float4 v = pw4[li];
            *(float4*)&wsh[li >> 4][(li & 15) * 4] = v;
        }
        __syncthreads();
        for (int k = 0; k < 64; k += 4) {
            float4 xv[4];
#pragma unroll
            for (int j = 0; j < 4; j++) xv[j] = *(const float4*)&xs[4 * rt + j][k];
#pragma unroll
            for (int kk = 0; kk < 4; kk++) {
                float4 wv = *(const float4*)&wsh[k + kk][4 * ct];
#pragma unroll
                for (int j = 0; j < 4; j++) {
                    float xx = kk == 0 ? xv[j].x : kk == 1 ? xv[j].y : kk == 2 ? xv[j].z : xv[j].w;
                    acc[j][0] = fmaf(xx, wv.x, acc[j][0]);
                    acc[j][1] = fmaf(xx, wv.y, acc[j][1]);
                    acc[j][2] = fmaf(xx, wv.z, acc[j][2]);
                    acc[j][3] = fmaf(xx, wv.w, acc[j][3]);
                }
            }
        }
        __syncthreads();
    }

    float4 pbv = *(const float4*)&pb[4 * ct];
    float z[4][4];
#pragma unroll
    for (int j = 0; j < 4; j++) {
        z[j][0] = acc[j][0] + pbv.x; z[j][1] = acc[j][1] + pbv.y;
        z[j][2] = acc[j][2] + pbv.z; z[j][3] = acc[j][3] + pbv.w;
        float4 hv;
        hv.x = 0.5f * z[j][0] * (1.f + erff(z[j][0] * 0.70710678118654752f));
        hv.y = 0.5f * z[j][1] * (1.f + erff(z[j][1] * 0.70710678118654752f));
        hv.z = 0.5f * z[j][2] * (1.f + erff(z[j][2] * 0.70710678118654752f));
        hv.w = 0.5f * z[j][3] * (1.f + erff(z[j][3] * 0.70710678118654752f));
        *(float4*)&hs[4 * rt + j][4 * ct] = hv;
    }
    const float4* w24 = (const float4*)w2;
    for (int li = tid; li < 1024; li += 256) {
        float4 v = w24[li];
        *(float4*)&wsh[li >> 4][(li & 15) * 4] = v;
    }
    __syncthreads();

    float4 b2v = *(const float4*)&b2[4 * ct];
    float acc2[4][4];
#pragma unroll
    for (int j = 0; j < 4; j++) {
        acc2[j][0] = z[j][0] + b2v.x; acc2[j][1] = z[j][1] + b2v.y;
        acc2[j][2] = z[j][2] + b2v.z; acc2[j][3] = z[j][3] + b2v.w;
    }
    for (int k = 0; k < 64; k += 4) {
        float4 xv[4];
#pragma unroll
        for (int j = 0; j < 4; j++) xv[j] = *(const float4*)&hs[4 * rt + j][k];
#pragma unroll
        for (int kk = 0; kk < 4; kk++) {
            float4 wv = *(const float4*)&wsh[k + kk][4 * ct];
#pragma unroll
            for (int j = 0; j < 4; j++) {
                float xx = kk == 0 ? xv[j].x : kk == 1 ? xv[j].y : kk == 2 ? xv[j].z : xv[j].w;
                acc2[j][0] = fmaf(xx, wv.x, acc2[j][0]);
                acc2[j][1] = fmaf(xx, wv.y, acc2[j][1]);
                acc2[j][2] = fmaf(xx, wv.z, acc2[j][2]);
                acc2[j][3] = fmaf(xx, wv.w, acc2[j][3]);
            }
        }
    }
    __syncthreads();
#pragma unroll
    for (int j = 0; j < 4; j++)
        *(float4*)&xs[4 * rt + j][4 * ct] = make_float4(acc2[j][0], acc2[j][1], acc2[j][2], acc2[j][3]);
    __syncthreads();

    int lane = tid & 63, wid = tid >> 6;
    float gc = g[lane], bec = be[lane];
    for (int rr = wid; rr < 64; rr += 4) {
        float y = xs[rr][lane];
        float mu = y;
        for (int off = 32; off; off >>= 1) mu += __shfl_xor(mu, off);
        mu *= (1.f / 64.f);
        float d = y - mu;
        float var = d * d;
        for (int off = 32; off; off >>= 1) var += __shfl_xor(var, off);
        var *= (1.f / 64.f);
        float o = d / sqrtf(var + 1e-5f) * gc + bec;
        int grow = row0 + rr;
        if (grow < nrows) feat[(long)idx[grow] * HIDD + lane] = __float2bfloat16(o);
    }
}

// ---------------- CSR build: hist -> scan -> binA (coarse) -> binB (exact) ----------------
__global__ void hist_kernel(const int* __restrict__ tgt_user, const int* __restrict__ tgt_item,
                            int* __restrict__ cnt)
{
    int combo = blockIdx.y;
    const int* tgt = (combo < 2 ? tgt_user : tgt_item) + (long)(combo & 1) * EEE;
    int i = blockIdx.x * 256 + threadIdx.x;
    if (i < EEE) atomicAdd(&cnt[combo * BBB + tgt[i]], 1);
}

__global__ __launch_bounds__(256) void scan_kernel(const int* __restrict__ cnt, int* __restrict__ offs,
                                                   int* __restrict__ cur32, float* __restrict__ s_acc)
{
    int pth = blockIdx.x;
    if (pth == 0 && threadIdx.x < 4) s_acc[threadIdx.x] = 0.f;
    const int* c = cnt + pth * BBB;
    int* o = offs + pth * (BBB + 1);
    __shared__ int part[256];
    int tid = threadIdx.x;
    int base = tid * 32;
    int local[32];
    int sum = 0;
    for (int j = 0; j < 32; j++) { local[j] = sum; sum += c[base + j]; }
    part[tid] = sum;
    __syncthreads();
    for (int d = 1; d < 256; d <<= 1) {
        int v = (tid >= d) ? part[tid - d] : 0;
        __syncthreads();
        part[tid] += v;
        __syncthreads();
    }
    int pre = (tid == 0) ? 0 : part[tid - 1];
    for (int j = 0; j < 32; j++) {
        int val = pre + local[j];
        o[base + j] = val;
        if (((base + j) & 255) == 0) cur32[pth * 32 + ((base + j) >> 8)] = val;
    }
    if (tid == 255) o[BBB] = pre + sum;
}

// pass A: bin instances into 32 coarse buckets (256 targets each), LDS-sorted, coalesced run writes
#define CHUNK 2048
__global__ __launch_bounds__(256) void binA_kernel(
    const int* __restrict__ tgt_user, const int* __restrict__ tgt_item,
    const int* __restrict__ emi_user, const int* __restrict__ emi_item,
    int* __restrict__ cur32, ushort4* __restrict__ binbuf)
{
    int combo = blockIdx.y;
    const int* tgt = (combo < 2 ? tgt_user : tgt_item) + (long)(combo & 1) * EEE;
    const int* emi = (combo < 2 ? emi_user : emi_item) + (long)(combo & 1) * EEE * 3;
    __shared__ ushort4 sbuf[CHUNK];
    __shared__ int lcnt[32], lofs[33], gbase[32], lcur[32];
    int tid = threadIdx.x;
    int base = blockIdx.x * CHUNK;
    if (tid < 32) { lcnt[tid] = 0; lcur[tid] = 0; }
    __syncthreads();
    ushort4 ent[8]; int bk[8];
#pragma unroll
    for (int ps = 0; ps < 8; ps++) {
        int i = base + ps * 256 + tid;
        if (i < EEE) {
            int t = tgt[i];
            ent[ps] = make_ushort4((unsigned short)emi[3 * i], (unsigned short)emi[3 * i + 1],
                                   (unsigned short)emi[3 * i + 2], (unsigned short)t);
            bk[ps] = t >> 8;
            atomicAdd(&lcnt[bk[ps]], 1);
        } else bk[ps] = -1;
    }
    __syncthreads();
    if (tid == 0) {
        int run = 0;
        for (int k = 0; k < 32; k++) { lofs[k] = run; run += lcnt[k]; }
        lofs[32] = run;
    }
    __syncthreads();
    if (tid < 32) gbase[tid] = atomicAdd(&cur32[combo * 32 + tid], lcnt[tid]);
    __syncthreads();
#pragma unroll
    for (int ps = 0; ps < 8; ps++) {
        if (bk[ps] >= 0) {
            int pos = lofs[bk[ps]] + atomicAdd(&lcur[bk[ps]], 1);
            sbuf[pos] = ent[ps];
        }
    }
    __syncthreads();
    int total = lofs[32];
    ushort4* dst = binbuf + (long)combo * EEE;
    for (int j = tid; j < total; j += 256) {
        ushort4 e = sbuf[j];
        int k = e.w >> 8;
        dst[gbase[k] + (j - lofs[k])] = e;
    }
}

// pass B: within each coarse bucket (contiguous ~50KB window), place entries at exact CSR position
__global__ __launch_bounds__(256) void binB_kernel(
    const int* __restrict__ offs, int* __restrict__ cur,
    const ushort4* __restrict__ binbuf, ushort4* __restrict__ nodes)
{
    int combo = blockIdx.y;
    int k = blockIdx.x >> 1, part = blockIdx.x & 1;
    const int* of = offs + combo * (BBB + 1);
    int rbeg = of[k << 8], rend = of[(k + 1) << 8];
    const ushort4* src = binbuf + (long)combo * EEE;
    ushort4* dst = nodes + (long)combo * EEE;
    int* cu = cur + combo * BBB;
    for (int j = rbeg + part * 256 + threadIdx.x; j < rend; j += 512) {
        ushort4 e = src[j];
        int t = e.w;
        int pos = of[t] + atomicAdd(&cu[t], 1);
        dst[pos] = e;
    }
}

// ---------------- flash metapath: gather + rotate + attention + online softmax + ELU ----------------
// one 64-lane wave per (target, combo); 8 instance streams per half (16/iter); 2-stage pipeline.
__global__ __launch_bounds__(256) void flash_mp(
    const __hip_bfloat16* __restrict__ feat, const ushort4* __restrict__ nodes,
    const int* __restrict__ offs, const float* __restrict__ r_vec,
    const float* __restrict__ attn_user, const float* __restrict__ attn_item,
    float* __restrict__ ret)
{
    int combo = blockIdx.y;
    int wid = threadIdx.x >> 6, lane = threadIdx.x & 63;
    int half = lane >> 5, p = lane & 31;
    int side = combo >> 1;
    const float* attn = (side == 0 ? attn_user : attn_item) + (combo & 1) * 64;
    const __hip_bfloat162* f2 = (const __hip_bfloat162*)feat;
    float2 rb = ((const float2*)r_vec)[p];
    float invn = 1.f / sqrtf(rb.x * rb.x + rb.y * rb.y);
    float rvx = rb.x * invn, rvy = rb.y * invn;
    if (side == 0) rvy = -rvy;
    float aRe = attn[2 * p], aIm = attn[2 * p + 1];
    int t = blockIdx.x * 4 + wid;
    int beg = offs[combo * (BBB + 1) + t], end = offs[combo * (BBB + 1) + t + 1];
    int n = end - beg;
    const ushort4* nd = nodes + (long)combo * EEE;

    float m = -3.4e38f, s = 0.f, Ox = 0.f, Oy = 0.f;

    __hip_bfloat162 c[8][3];
    ushort4 nq[8];
    if (n > 0) {
#pragma unroll
        for (int q = 0; q < 8; q++) {
            int j = beg + 2 * q + half; if (j >= end) j = end - 1;
            ushort4 a = nd[j];
            c[q][0] = f2[(int)a.x * 32 + p];
            c[q][1] = f2[(int)a.y * 32 + p];
            c[q][2] = f2[(int)a.z * 32 + p];
        }
#pragma unroll
        for (int q = 0; q < 8; q++) {
            int j = beg + 16 + 2 * q + half; if (j >= end) j = end - 1;
            nq[q] = nd[j];
        }
    }
    for (int it = 0; it < n; it += 16) {
        float2 u[8][3];
#pragma unroll
        for (int q = 0; q < 8; q++)
#pragma unroll
            for (int r = 0; r < 3; r++)
                u[q][r] = __bfloat1622float2(c[q][r]);
        if (it + 16 < n) {
#pragma unroll
            for (int q = 0; q < 8; q++) {
                c[q][0] = f2[(int)nq[q].x * 32 + p];
                c[q][1] = f2[(int)nq[q].y * 32 + p];
                c[q][2] = f2[(int)nq[q].z * 32 + p];
            }
#pragma unroll
            for (int q = 0; q < 8; q++) {
                int j = beg + it + 32 + 2 * q + half; if (j >= end) j = end - 1;
                nq[q] = nd[j];
            }
        }
        float re[8], im[8], e[8];
#pragma unroll
        for (int q = 0; q < 8; q++) {
            re[q] = (u[q][0].x + u[q][2].x + u[q][1].x * rvx - u[q][1].y * rvy) * (1.f / 3.f);
            im[q] = (u[q][0].y + u[q][2].y + u[q][1].x * rvy + u[q][1].y * rvx) * (1.f / 3.f);
            float pa = re[q] * aRe + im[q] * aIm;
            pa += __shfl_xor(pa, 1);
            pa += __shfl_xor(pa, 2);
            float ev = pa > 0.f ? pa : 0.01f * pa;       // leaky_relu
            if (it + 2 * q + half >= n) ev = -3.4e38f;
            e[q] = ev;
        }
        float mx = e[0];
#pragma unroll
        for (int q = 1; q < 8; q++) mx = fmaxf(mx, e[q]);
        float mn = fmaxf(m, fmaxf(mx, __shfl_xor(mx, 32)));
        float alpha = __expf(m - mn);
        float wl = 0.f, ax = 0.f, ay = 0.f;
#pragma unroll
        for (int q = 0; q < 8; q++) {
            float w = __expf(e[q] - mn);
            wl += w; ax = fmaf(w, re[q], ax); ay = fmaf(w, im[q], ay);
        }
        s = s * alpha + wl + __shfl_xor(wl, 32);
        Ox = Ox * alpha + ax;
        Oy = Oy * alpha + ay;
        m = mn;
    }
    float sx = __shfl_xor(Ox, 32), sy = __shfl_xor(Oy, 32);
    float inv = 1.f / (s + 1e-9f);
    float vx = (Ox + sx) * inv, vy = (Oy + sy) * inv;
    vx = vx > 0.f ? vx : __expf(vx) - 1.f;   // ELU
    vy = vy > 0.f ? vy : __expf(vy) - 1.f;
    if (half == 0)
        ((float2*)ret)[((long)combo * BBB + t) * 32 + p] = make_float2(vx, vy);
}

// ---------------- semantic score GEMM: s_acc[combo] = sum_b tanh(ret_b @ w1 + b1) @ w2 ----------------
__global__ __launch_bounds__(256) void sem_kernel(
    const float* __restrict__ ret,
    const float* __restrict__ su_w1, const float* __restrict__ su_b1, const float* __restrict__ su_w2,
    const float* __restrict__ si_w1, const float* __restrict__ si_b1, const float* __restrict__ si_w2,
    float* __restrict__ s_acc)
{
    int combo = blockIdx.y;
    int side = combo >> 1;
    const float* w1 = side ? si_w1 : su_w1;
    const float* b1 = side ? si_b1 : su_b1;
    const float* w2 = side ? si_w2 : su_w2;
    __shared__ float vs[64][68];
    __shared__ float w1s[64][128];
    int tid = threadIdx.x;
    int rowbase = blockIdx.x * 64;
    const float4* r4 = (const float4*)ret;
    for (int li = tid; li < 1024; li += 256) {
        int r = li >> 4, c4 = li & 15;
        float4 v = r4[((long)combo * BBB + rowbase + r) * 16 + c4];
        *(float4*)&vs[r][c4 * 4] = v;
    }
    const float4* w14 = (const float4*)w1;
    for (int li = tid; li < 2048; li += 256) {
        float4 v = w14[li];
        *(float4*)&w1s[li >> 5][(li & 31) * 4] = v;
    }
    __syncthreads();
    int ct = tid & 15, rt = tid >> 4;
    float acc[4][8];
#pragma unroll
    for (int cc = 0; cc < 8; cc++) {
        float b = b1[8 * ct + cc];
#pragma unroll
        for (int j = 0; j < 4; j++) acc[j][cc] = b;
    }
    for (int k = 0; k < 64; k += 4) {
        float4 xv[4];
#pragma unroll
        for (int j = 0; j < 4; j++) xv[j] = *(const float4*)&vs[4 * rt + j][k];
#pragma unroll
        for (int kk = 0; kk < 4; kk++) {
            float4 wv0 = *(const float4*)&w1s[k + kk][8 * ct];
            float4 wv1 = *(const float4*)&w1s[k + kk][8 * ct + 4];
#pragma unroll
            for (int j = 0; j < 4; j++) {
                float xx = kk == 0 ? xv[j].x : kk == 1 ? xv[j].y : kk == 2 ? xv[j].z : xv[j].w;
                acc[j][0] = fmaf(xx, wv0.x, acc[j][0]);
                acc[j][1] = fmaf(xx, wv0.y, acc[j][1]);
                acc[j][2] = fmaf(xx, wv0.z, acc[j][2]);
                acc[j][3] = fmaf(xx, wv0.w, acc[j][3]);
                acc[j][4] = fmaf(xx, wv1.x, acc[j][4]);
                acc[j][5] = fmaf(xx, wv1.y, acc[j][5]);
                acc[j][6] = fmaf(xx, wv1.z, acc[j][6]);
                acc[j][7] = fmaf(xx, wv1.w, acc[j][7]);
            }
        }
    }
    float tot = 0.f;
#pragma unroll
    for (int cc = 0; cc < 8; cc++) {
        float w2v = w2[8 * ct + cc];
#pragma unroll
        for (int j = 0; j < 4; j++) tot += fast_tanh(acc[j][cc]) * w2v;
    }
    for (int off = 32; off; off >>= 1) tot += __shfl_xor(tot, off);
    __shared__ float red[4];
    int lane = tid & 63, wid = tid >> 6;
    if (lane == 0) red[wid] = tot;
    __syncthreads();
    if (tid == 0) atomicAdd(&s_acc[combo], red[0] + red[1] + red[2] + red[3]);
}

// ---------------- final product MLP + softmax (beta inline, GEMM-tiled) ----------------
__global__ __launch_bounds__(256) void final_kernel(
    const float* __restrict__ ret, const float* __restrict__ s_acc,
    const float* __restrict__ cw1, const float* __restrict__ cb1, const float* __restrict__ cw2,
    float* __restrict__ outp)
{
    float s0 = s_acc[0] * (1.f / BBB), s1 = s_acc[1] * (1.f / BBB);
    float s2 = s_acc[2] * (1.f / BBB), s3 = s_acc[3] * (1.f / BBB);
    float mu = fmaxf(s0, s1);
    float e0 = __expf(s0 - mu), e1 = __expf(s1 - mu);
    float bu0 = e0 / (e0 + e1), bu1 = e1 / (e0 + e1);
    float mi = fmaxf(s2, s3);
    float f0 = __expf(s2 - mi), f1 = __expf(s3 - mi);
    float bi0 = f0 / (f0 + f1), bi1 = f1 / (f0 + f1);

    __shared__ float xsld[64][68];
    __shared__ float w1s[64][128];
    int tid = threadIdx.x;
    int rowbase = blockIdx.x * 64;
    const float4* r4 = (const float4*)ret;
    for (int li = tid; li < 1024; li += 256) {
        int r = li >> 4, c4 = li & 15;
        float4 a = r4[((long)0 * BBB + rowbase + r) * 16 + c4];
        float4 b = r4[((long)1 * BBB + rowbase + r) * 16 + c4];
        float4 cc = r4[((long)2 * BBB + rowbase + r) * 16 + c4];
        float4 d = r4[((long)3 * BBB + rowbase + r) * 16 + c4];
        float4 xv;
        xv.x = (bu0 * a.x + bu1 * b.x) * (bi0 * cc.x + bi1 * d.x);
        xv.y = (bu0 * a.y + bu1 * b.y) * (bi0 * cc.y + bi1 * d.y);
        xv.z = (bu0 * a.z + bu1 * b.z) * (bi0 * cc.z + bi1 * d.z);
        xv.w = (bu0 * a.w + bu1 * b.w) * (bi0 * cc.w + bi1 * d.w);
        *(float4*)&xsld[r][c4 * 4] = xv;
    }
    const float4* w14 = (const float4*)cw1;
    for (int li = tid; li < 2048; li += 256) {
        float4 v = w14[li];
        *(float4*)&w1s[li >> 5][(li & 31) * 4] = v;
    }
    __syncthreads();
    int ct = tid & 15, rt = tid >> 4;
    float acc[4][8];
#pragma unroll
    for (int cc = 0; cc < 8; cc++) {
        float b = cb1[8 * ct + cc];
#pragma unroll
        for (int j = 0; j < 4; j++) acc[j][cc] = b;
    }
    for (int k = 0; k < 64; k += 4) {
        float4 xv[4];
#pragma unroll
        for (int j = 0; j < 4; j++) xv[j] = *(const float4*)&xsld[4 * rt + j][k];
#pragma unroll
        for (int kk = 0; kk < 4; kk++) {
            float4 wv0 = *(const float4*)&w1s[k + kk][8 * ct];
            float4 wv1 = *(const float4*)&w1s[k + kk][8 * ct + 4];
#pragma unroll
            for (int j = 0; j < 4; j++) {
                float xx = kk == 0 ? xv[j].x : kk == 1 ? xv[j].y : kk == 2 ? xv[j].z : xv[j].w;
                acc[j][0] = fmaf(xx, wv0.x, acc[j][0]);
                acc[j][1] = fmaf(xx, wv0.y, acc[j][1]);
                acc[j][2] = fmaf(xx, wv0.z, acc[j][2]);
                acc[j][3] = fmaf(xx, wv0.w, acc[j][3]);
                acc[j][4] = fmaf(xx, wv1.x, acc[j][4]);
                acc[j][5] = fmaf(xx, wv1.y, acc[j][5]);
                acc[j][6] = fmaf(xx, wv1.z, acc[j][6]);
                acc[j][7] = fmaf(xx, wv1.w, acc[j][7]);
            }
        }
    }
    float pp0[4], pp1[4];
#pragma unroll
    for (int j = 0; j < 4; j++) { pp0[j] = 0.f; pp1[j] = 0.f; }
#pragma unroll
    for (int cc = 0; cc < 8; cc++) {
        int col = 8 * ct + cc;
        float c0 = cw2[col * 2], c1 = cw2[col * 2 + 1];
#pragma unroll
        for (int j = 0; j < 4; j++) {
            float h = fmaxf(acc[j][cc], 0.f);
            pp0[j] = fmaf(h, c0, pp0[j]);
            pp1[j] = fmaf(h, c1, pp1[j]);
        }
    }
    __syncthreads();
    float2* red = (float2*)xsld;   // 64 rows x 16 = 2048 float2, fits in xsld
#pragma unroll
    for (int j = 0; j < 4; j++)
        red[(4 * rt + j) * 16 + ct] = make_float2(pp0[j], pp1[j]);
    __syncthreads();
    if (tid < 64) {
        float q0 = 0.f, q1 = 0.f;
        for (int i = 0; i < 16; i++) {
            float2 e = red[tid * 16 + i];
            q0 += e.x; q1 += e.y;
        }
        float mx = fmaxf(q0, q1);
        float a0 = __expf(q0 - mx), a1 = __expf(q1 - mx);
        float dn = a0 + a1;
        outp[(rowbase + tid) * 2] = a0 / dn;
        outp[(rowbase + tid) * 2 + 1] = a1 / dn;
    }
}

extern "C" void kernel_launch(void* const* d_in, const int* in_sizes, int n_in,
                              void* d_out, int out_size, void* d_ws, size_t ws_size,
                              hipStream_t stream)
{
    const float* feats0 = (const float*)d_in[0];
    const float* feats1 = (const float*)d_in[1];
    const float* t0_pw = (const float*)d_in[2];
    const float* t0_pb = (const float*)d_in[3];
    const float* t0_w2 = (const float*)d_in[4];
    const float* t0_b2 = (const float*)d_in[5];
    const float* t0_g  = (const float*)d_in[6];
    const float* t0_be = (const float*)d_in[7];
    const float* t1_pw = (const float*)d_in[8];
    const float* t1_pb = (const float*)d_in[9];
    const float* t1_w2 = (const float*)d_in[10];
    const float* t1_b2 = (const float*)d_in[11];
    const float* t1_g  = (const float*)d_in[12];
    const float* t1_be = (const float*)d_in[13];
    const float* r_vec = (const float*)d_in[14];
    const float* attn_user = (const float*)d_in[15];
    const float* attn_item = (const float*)d_in[16];
    const float* su_w1 = (const float*)d_in[17];
    const float* su_b1 = (const float*)d_in[18];
    const float* su_w2 = (const float*)d_in[19];
    const float* si_w1 = (const float*)d_in[20];
    const float* si_b1 = (const float*)d_in[21];
    const float* si_w2 = (const float*)d_in[22];
    const float* cw1 = (const float*)d_in[23];
    const float* cb1 = (const float*)d_in[24];
    const float* cw2 = (const float*)d_in[25];
    const int* idx0 = (const int*)d_in[26];
    const int* idx1 = (const int*)d_in[27];
    const int* emi_user = (const int*)d_in[28];
    const int* tgt_user = (const int*)d_in[29];
    const int* emi_item = (const int*)d_in[30];
    const int* tgt_item = (const int*)d_in[31];
    float* outp = (float*)d_out;

    // workspace layout (256B aligned)
    char* ws = (char*)d_ws;
    __hip_bfloat16* feat = (__hip_bfloat16*)(ws + 0);   // 5,120,000
    int*     cnt    = (int*)(ws + 5120000);             // 131,072
    int*     cur    = (int*)(ws + 5251072);             // 131,072 (contiguous with cnt for one memset)
    int*     cur32  = (int*)(ws + 5382144);             // 512
    int*     offs   = (int*)(ws + 5382656);             // 131,088 -> pad 131,328
    float*   s_acc  = (float*)(ws + 5513984);           // 256
    ushort4* binbuf = (ushort4*)(ws + 5514240);         // 6,400,000
    ushort4* nodes  = (ushort4*)(ws + 11914240);        // 6,400,000
    float*   ret_buf= (float*)(ws + 18314240);          // 8,388,608  (end ~26.7 MB)

    tower_kernel<<<dim3((NN0 + 63) / 64, 2), 256, 0, stream>>>(
        feats0, feats1, t0_pw, t1_pw, t0_pb, t1_pb, t0_w2, t1_w2,
        t0_b2, t1_b2, t0_g, t1_g, t0_be, t1_be, idx0, idx1, feat);

    hipMemsetAsync(cnt, 0, 2 * 4 * BBB * sizeof(int), stream);
    hist_kernel<<<dim3((EEE + 255) / 256, 4), 256, 0, stream>>>(tgt_user, tgt_item, cnt);
    scan_kernel<<<4, 256, 0, stream>>>(cnt, offs, cur32, s_acc);
    binA_kernel<<<dim3((EEE + CHUNK - 1) / CHUNK, 4), 256, 0, stream>>>(
        tgt_user, tgt_item, emi_user, emi_item, cur32, binbuf);
    binB_kernel<<<dim3(64, 4), 256, 0, stream>>>(offs, cur, binbuf, nodes);

    flash_mp<<<dim3(BBB / 4, 4), 256, 0, stream>>>(feat, nodes, offs, r_vec,
                                                   attn_user, attn_item, ret_buf);

    sem_kernel<<<dim3(BBB / 64, 4), 256, 0, stream>>>(ret_buf, su_w1, su_b1, su_w2,
                                                      si_w1, si_b1, si_w2, s_acc);
    final_kernel<<<BBB / 64, 256, 0, stream>>>(ret_buf, s_acc, cw1, cb1, cw2, outp);
}